// Round 10
// baseline (200.430 us; speedup 1.0000x reference)
//
#include <hip/hip_runtime.h>
#include <math.h>

#define B_ 16
#define N_ 4096

typedef __attribute__((ext_vector_type(8))) short short8v;
typedef __attribute__((ext_vector_type(4))) short short4v;
typedef __attribute__((ext_vector_type(4))) float f32x4;

__device__ __forceinline__ unsigned short f2bf(float f) {
  unsigned int u = __float_as_uint(f);
  return (unsigned short)((u + 0x7FFFu + ((u >> 16) & 1u)) >> 16);
}

// pack two fp32 -> one dword of two bf16 (lo = first, hi = second)
__device__ __forceinline__ unsigned int pk2(float a, float b) {
  return (unsigned int)f2bf(a) | ((unsigned int)f2bf(b) << 16);
}

// convert 8 consecutive fp32 -> bf16x8 fragment
__device__ __forceinline__ short8v cvt8f(const float* p) {
  float4 a = *reinterpret_cast<const float4*>(p);
  float4 b = *reinterpret_cast<const float4*>(p + 4);
  short8v r;
  r[0] = (short)f2bf(a.x); r[1] = (short)f2bf(a.y);
  r[2] = (short)f2bf(a.z); r[3] = (short)f2bf(a.w);
  r[4] = (short)f2bf(b.x); r[5] = (short)f2bf(b.y);
  r[6] = (short)f2bf(b.z); r[7] = (short)f2bf(b.w);
  return r;
}

// ---------------- square weights -> bf16 (R3 exact) ------------------------
__global__ __launch_bounds__(256) void cvt_w(const float* __restrict__ a,
    const float* __restrict__ b, const float* __restrict__ c,
    const float* __restrict__ d, unsigned short* __restrict__ wa,
    unsigned short* __restrict__ wb, unsigned short* __restrict__ wc,
    unsigned short* __restrict__ wd) {
  int i = blockIdx.x * 256 + threadIdx.x;
  int j = i & 16383;
  if (i < 16384) wa[j] = f2bf(a[j]);
  else if (i < 32768) wb[j] = f2bf(b[j]);
  else if (i < 49152) wc[j] = f2bf(c[j]);
  else wd[j] = f2bf(d[j]);
}

// ---- x (b,4096,128) fp32 -> xT (b,128,4096) bf16 (R7 exact) ---------------
__global__ __launch_bounds__(256) void transpose_bf(const float* __restrict__ x,
    unsigned short* __restrict__ xT) {
  __shared__ float lds[32 * 132];
  const int t = threadIdx.x;
  const int b = blockIdx.x >> 7, pt = blockIdx.x & 127;
  const int ptile = pt * 32;
  for (int i = t; i < 1024; i += 256) {
    int p = i >> 5, c4 = (i & 31) << 2;
    *reinterpret_cast<float4*>(&lds[p * 132 + c4]) =
        *reinterpret_cast<const float4*>(
            x + ((size_t)(b * 4096 + ptile + p)) * 128 + c4);
  }
  __syncthreads();
  const int c = t >> 1, p0 = (t & 1) * 16;
  unsigned short* dst = xT + (size_t)b * 524288 + c * 4096 + ptile + p0;
  uint4 u0, u1;
  u0.x = pk2(lds[(p0 + 0) * 132 + c], lds[(p0 + 1) * 132 + c]);
  u0.y = pk2(lds[(p0 + 2) * 132 + c], lds[(p0 + 3) * 132 + c]);
  u0.z = pk2(lds[(p0 + 4) * 132 + c], lds[(p0 + 5) * 132 + c]);
  u0.w = pk2(lds[(p0 + 6) * 132 + c], lds[(p0 + 7) * 132 + c]);
  u1.x = pk2(lds[(p0 + 8) * 132 + c], lds[(p0 + 9) * 132 + c]);
  u1.y = pk2(lds[(p0 + 10) * 132 + c], lds[(p0 + 11) * 132 + c]);
  u1.z = pk2(lds[(p0 + 12) * 132 + c], lds[(p0 + 13) * 132 + c]);
  u1.w = pk2(lds[(p0 + 14) * 132 + c], lds[(p0 + 15) * 132 + c]);
  *reinterpret_cast<uint4*>(dst) = u0;
  *reinterpret_cast<uint4*>(dst + 8) = u1;
}

// ---------- patchify conv as MFMA GEMM, K-split partials (R7 exact) --------
template <int SRV, int KSP>
__global__ __launch_bounds__(256) void convgemm_mfma(
    const unsigned short* __restrict__ xT, const float* __restrict__ W,
    float* __restrict__ part) {
  constexpr int WP = 64 / SRV;
  constexpr int M = WP * WP;
  constexpr int ROWS = B_ * M;
  constexpr int SS = SRV * SRV;
  constexpr int KTOT = 128 * SS;
  constexpr int LSS = (SRV == 8) ? 6 : 4;
  constexpr int LM = (SRV == 8) ? 6 : 8;
  constexpr int LWP = (SRV == 8) ? 3 : 4;
  const int t = threadIdx.x;
  const int wid = t >> 6, lane = t & 63;
  const int lrow = lane & 15, lk = (lane >> 4) << 3;
  const int r0 = blockIdx.x * 128 + wid * 32;
  const int kb0 = blockIdx.y * KSP;
  int rbase[2], pixoff[2];
#pragma unroll
  for (int m = 0; m < 2; m++) {
    int row = r0 + m * 16 + lrow;
    int b = row >> LM, p = row & (M - 1);
    int ph = p >> LWP, pw = p & (WP - 1);
    rbase[m] = b << 19;
    pixoff[m] = (ph * SRV) * 64 + pw * SRV;
  }
  f32x4 acc[2][8];
#pragma unroll
  for (int m = 0; m < 2; m++)
#pragma unroll
    for (int n = 0; n < 8; n++) acc[m][n] = (f32x4)(0.f);
  for (int k0 = 0; k0 < KSP; k0 += 32) {
    int k = kb0 + k0 + lk;
    int ci = k >> LSS;
    int rem = k & (SS - 1);
    short8v a[2], bf[8];
#pragma unroll
    for (int m = 0; m < 2; m++) {
      if constexpr (SRV == 8) {
        a[m] = *reinterpret_cast<const short8v*>(
            xT + (size_t)rbase[m] + ci * 4096 + pixoff[m] + (rem >> 3) * 64);
      } else {
        int kh0 = rem >> 2;
        short4v lo = *reinterpret_cast<const short4v*>(
            xT + (size_t)rbase[m] + ci * 4096 + pixoff[m] + kh0 * 64);
        short4v hi = *reinterpret_cast<const short4v*>(
            xT + (size_t)rbase[m] + ci * 4096 + pixoff[m] + (kh0 + 1) * 64);
        short8v av;
        av[0] = lo[0]; av[1] = lo[1]; av[2] = lo[2]; av[3] = lo[3];
        av[4] = hi[0]; av[5] = hi[1]; av[6] = hi[2]; av[7] = hi[3];
        a[m] = av;
      }
    }
#pragma unroll
    for (int n = 0; n < 8; n++)
      bf[n] = cvt8f(W + (size_t)(n * 16 + lrow) * KTOT + k);
#pragma unroll
    for (int m = 0; m < 2; m++)
#pragma unroll
      for (int n = 0; n < 8; n++)
        acc[m][n] = __builtin_amdgcn_mfma_f32_16x16x32_bf16(a[m], bf[n],
                                                            acc[m][n], 0, 0, 0);
  }
  const int rr = (lane >> 4) << 2;
#pragma unroll
  for (int m = 0; m < 2; m++)
#pragma unroll
    for (int n = 0; n < 8; n++) {
      int c = n * 16 + lrow;
#pragma unroll
      for (int j = 0; j < 4; j++)
        part[((size_t)blockIdx.y * ROWS + r0 + m * 16 + rr + j) * 128 + c] =
            acc[m][n][j];
    }
}

// ------------- MFMA GEMM (R3 exact): out[r][c] = sum_k A[r][k] * W[c][k] ---
template <bool HAS_BIAS>
__global__ __launch_bounds__(256) void gemm_mfma(const float* __restrict__ A,
    const unsigned short* __restrict__ W, const float* __restrict__ bias,
    float* __restrict__ out) {
  const int t = threadIdx.x;
  const int wid = t >> 6, lane = t & 63;
  const int lrow = lane & 15, lk = (lane >> 4) << 3;
  const int r0 = blockIdx.x * 128 + wid * 32;
  f32x4 acc[2][8];
#pragma unroll
  for (int m = 0; m < 2; m++)
#pragma unroll
    for (int n = 0; n < 8; n++) acc[m][n] = (f32x4)(0.f);
#pragma unroll
  for (int k0 = 0; k0 < 128; k0 += 32) {
    short8v a[2], bf[8];
#pragma unroll
    for (int m = 0; m < 2; m++)
      a[m] = cvt8f(A + (size_t)(r0 + m * 16 + lrow) * 128 + k0 + lk);
#pragma unroll
    for (int n = 0; n < 8; n++)
      bf[n] = *reinterpret_cast<const short8v*>(
          W + (size_t)(n * 16 + lrow) * 128 + k0 + lk);
#pragma unroll
    for (int m = 0; m < 2; m++)
#pragma unroll
      for (int n = 0; n < 8; n++)
        acc[m][n] = __builtin_amdgcn_mfma_f32_16x16x32_bf16(a[m], bf[n],
                                                            acc[m][n], 0, 0, 0);
  }
  const int rr = (lane >> 4) << 2;
#pragma unroll
  for (int m = 0; m < 2; m++)
#pragma unroll
    for (int n = 0; n < 8; n++) {
      int c = n * 16 + lrow;
      float bv = HAS_BIAS ? bias[c] : 0.f;
#pragma unroll
      for (int j = 0; j < 4; j++)
        out[(size_t)(r0 + m * 16 + rr + j) * 128 + c] = acc[m][n][j] + bv;
    }
}

// ---- reduce K-split partials + conv bias, LayerNorm(128) + exact GELU -----
__global__ __launch_bounds__(128) void ln_gelu(const float* __restrict__ part,
    int nsplit, int rows, const float* __restrict__ cb,
    const float* __restrict__ g, const float* __restrict__ be,
    float* __restrict__ out) {
  const int row = blockIdx.x;
  const int t = threadIdx.x;
  float v = cb[t];
  for (int s = 0; s < nsplit; s++)
    v += part[((size_t)s * rows + row) * 128 + t];
  float sv = v, sq = v * v;
#pragma unroll
  for (int off = 32; off > 0; off >>= 1) {
    sv += __shfl_down(sv, off, 64);
    sq += __shfl_down(sq, off, 64);
  }
  __shared__ float red0[2], red1[2];
  if ((t & 63) == 0) {
    red0[t >> 6] = sv;
    red1[t >> 6] = sq;
  }
  __syncthreads();
  float mean = (red0[0] + red0[1]) * (1.f / 128.f);
  float var = (red1[0] + red1[1]) * (1.f / 128.f) - mean * mean;
  float y = (v - mean) * rsqrtf(var + 1e-5f) * g[t] + be[t];
  out[(size_t)row * 128 + t] = y * 0.5f * (1.f + erff(y * 0.70710678118f));
}

// --------- depthwise 3x3 (pad 1) on v; v' = v + conv (R3 exact) ------------
template <int WP>
__global__ __launch_bounds__(256) void dwconv(const float* __restrict__ kv,
    const float* __restrict__ lw, const float* __restrict__ lb,
    float* __restrict__ vp) {
  constexpr int M = WP * WP;
  constexpr int LM = (WP == 8) ? 6 : 8;
  constexpr int LWPc = (WP == 8) ? 3 : 4;
  int idx = blockIdx.x * 256 + threadIdx.x;
  int ch = idx & 63;
  int rest = idx >> 6;
  int m = rest & (M - 1);
  int bb = rest >> LM;
  int y = m >> LWPc, x0 = m & (WP - 1);
  float s = lb[ch];
#pragma unroll
  for (int ky = 0; ky < 3; ky++) {
    int yy = y + ky - 1;
    if (yy < 0 || yy >= WP) continue;
#pragma unroll
    for (int kx = 0; kx < 3; kx++) {
      int xx = x0 + kx - 1;
      if (xx < 0 || xx >= WP) continue;
      s += kv[((size_t)(bb * M + yy * WP + xx)) * 128 + 64 + ch] *
           lw[ch * 9 + ky * 3 + kx];
    }
  }
  vp[idx] = kv[((size_t)(bb * M + m)) * 128 + 64 + ch] + s;
}

// ---- vp (b, m, 64) fp32 -> vT (b, 64ch, M) bf16: vT[b][c][m] = vp[b][m][c] --
// 32-m tiles (LDS 32x68 fp32 = 8.7K floats = 34.8 KB < 64 KB).
template <int M>
__global__ __launch_bounds__(256) void transpose_v(const float* __restrict__ vp,
    unsigned short* __restrict__ vT) {
  constexpr int TPB = M / 32;
  __shared__ float lds[32 * 68];
  const int t = threadIdx.x;
  const int blk = blockIdx.x;
  const int b = blk / TPB, mt = blk % TPB;
  const int m0 = mt * 32;
  for (int i = t; i < 512; i += 256) {
    int m = i >> 4, c4 = (i & 15) << 2;
    *reinterpret_cast<float4*>(&lds[m * 68 + c4]) =
        *reinterpret_cast<const float4*>(vp + ((size_t)(b * M + m0 + m)) * 64 + c4);
  }
  __syncthreads();
  const int c = t >> 2, ms = (t & 3) * 8;
  unsigned short* dst = vT + ((size_t)b * 64 + c) * M + m0 + ms;
  uint4 u;
  u.x = pk2(lds[(ms + 0) * 68 + c], lds[(ms + 1) * 68 + c]);
  u.y = pk2(lds[(ms + 2) * 68 + c], lds[(ms + 3) * 68 + c]);
  u.z = pk2(lds[(ms + 4) * 68 + c], lds[(ms + 5) * 68 + c]);
  u.w = pk2(lds[(ms + 6) * 68 + c], lds[(ms + 7) * 68 + c]);
  *reinterpret_cast<uint4*>(dst) = u;
}

// ------------- MFMA fused attention v2 (no V staging, no barrier) ----------
// Per block: 64 q-rows (4 waves x 16), one (b,h). S^T = mfma(K-rows, Q-rows).
// Softmax: per-lane partials + 2 shfl_xor. P -> per-wave LDS, PSTR = M+8
// shorts (rows 16B-aligned; row-start bank = 4*lrow mod 32 -> 2-way max,
// free). PV A-fragments (V^T rows) read straight from global vT.
template <int M, int QOFF>
__global__ __launch_bounds__(256) void attn_mfma(const float* __restrict__ q,
    const float* __restrict__ kv, const unsigned short* __restrict__ vT,
    float* __restrict__ xcat) {
  constexpr int PSTR = M + 8;
  constexpr int MT = M / 16;     // S^T m-tiles
  constexpr int PVS = M / 32;    // PV k-steps
  __shared__ unsigned short Pl[4][16 * PSTR];
  const int t = threadIdx.x;
  const int wid = t >> 6, lane = t & 63;
  const int lrow = lane & 15, g = lane >> 4;
  const int lk = g * 8;
  const int h = blockIdx.y, b = blockIdx.z;
  const size_t bm = (size_t)b * M;
  // ---- Q fragment (16 q-rows per wave) ----
  const int q0 = blockIdx.x * 64 + wid * 16;
  short8v qf = cvt8f(q + ((size_t)b * 4096 + q0 + lrow) * 128 + QOFF + h * 32 + lk);
  // ---- S^T tiles: K fragments direct from global (L2-resident) ----
  f32x4 s[MT];
#pragma unroll
  for (int mt = 0; mt < MT; mt++) {
    short8v kf = cvt8f(kv + (bm + mt * 16 + lrow) * 128 + h * 32 + lk);
    s[mt] = __builtin_amdgcn_mfma_f32_16x16x32_bf16(kf, qf, (f32x4)(0.f), 0, 0, 0);
  }
  // ---- softmax over m (lane holds q-col lrow, m = mt*16 + 4g + j) ----
  const float scale = 0.17677669529663687f;  // 1/sqrt(32)
  float l = 0.f;
#pragma unroll
  for (int mt = 0; mt < MT; mt++)
#pragma unroll
    for (int j = 0; j < 4; j++) {
      float p = __expf(s[mt][j] * scale);
      s[mt][j] = p;
      l += p;
    }
  l += __shfl_xor(l, 16, 64);
  l += __shfl_xor(l, 32, 64);
  // ---- write P (bf16) to per-wave LDS: row = q-local, col = m ----
#pragma unroll
  for (int mt = 0; mt < MT; mt++) {
    uint2 pw;
    pw.x = pk2(s[mt][0], s[mt][1]);
    pw.y = pk2(s[mt][2], s[mt][3]);
    *reinterpret_cast<uint2*>(&Pl[wid][lrow * PSTR + mt * 16 + 4 * g]) = pw;
  }
  // ---- PV: out^T[d][q], V^T fragments from global ----
  f32x4 o[2];
  o[0] = (f32x4)(0.f);
  o[1] = (f32x4)(0.f);
#pragma unroll
  for (int ks = 0; ks < PVS; ks++) {
    short8v pf = *reinterpret_cast<const short8v*>(
        &Pl[wid][lrow * PSTR + ks * 32 + lk]);
#pragma unroll
    for (int dt = 0; dt < 2; dt++) {
      short8v vf = *reinterpret_cast<const short8v*>(
          vT + ((size_t)b * 64 + h * 32 + dt * 16 + lrow) * M + ks * 32 + lk);
      o[dt] = __builtin_amdgcn_mfma_f32_16x16x32_bf16(vf, pf, o[dt], 0, 0, 0);
    }
  }
  // ---- store: lane holds q-col lrow, d-rows dt*16 + 4g + j ----
  float linv = 1.f / l;
  float* orow = xcat + ((size_t)b * 4096 + q0 + lrow) * 128 + QOFF + h * 32;
#pragma unroll
  for (int dt = 0; dt < 2; dt++) {
    float4 o4;
    o4.x = o[dt][0] * linv;
    o4.y = o[dt][1] * linv;
    o4.z = o[dt][2] * linv;
    o4.w = o[dt][3] * linv;
    *reinterpret_cast<float4*>(orow + dt * 16 + 4 * g) = o4;
  }
}

extern "C" void kernel_launch(void* const* d_in, const int* in_sizes, int n_in,
                              void* d_out, int out_size, void* d_ws,
                              size_t ws_size, hipStream_t stream) {
  (void)in_sizes; (void)n_in; (void)out_size; (void)ws_size;
  const float* x      = (const float*)d_in[0];
  const float* q_w    = (const float*)d_in[1];
  const float* sr1_w  = (const float*)d_in[2];
  const float* sr1_b  = (const float*)d_in[3];
  const float* n1_g   = (const float*)d_in[4];
  const float* n1_b   = (const float*)d_in[5];
  const float* sr2_w  = (const float*)d_in[6];
  const float* sr2_b  = (const float*)d_in[7];
  const float* n2_g   = (const float*)d_in[8];
  const float* n2_b   = (const float*)d_in[9];
  const float* kv1_w  = (const float*)d_in[10];
  const float* kv2_w  = (const float*)d_in[11];
  const float* lc1_w  = (const float*)d_in[12];
  const float* lc1_b  = (const float*)d_in[13];
  const float* lc2_w  = (const float*)d_in[14];
  const float* lc2_b  = (const float*)d_in[15];
  const float* proj_w = (const float*)d_in[16];
  const float* proj_b = (const float*)d_in[17];

  char* w = (char*)d_ws;
  unsigned short* wq    = (unsigned short*)(w);             // 32 KB
  unsigned short* wkv1  = (unsigned short*)(w + 32768);
  unsigned short* wkv2  = (unsigned short*)(w + 65536);
  unsigned short* wproj = (unsigned short*)(w + 98304);     // ends 131072
  float* qbuf = (float*)(w + 131072);                       // 33.55 MB
  unsigned short* xT = (unsigned short*)(w + 131072);       // aliases qbuf head
  float* xcat = (float*)(w + 33685504);                     // 33.55 MB
  float* part1 = xcat;
  float* part2 = xcat + 4194304;
  float* t1   = (float*)(w + 69468160);                     // 512 KB
  float* t2   = (float*)(w + 69992448);                     // 2 MB
  float* kv1  = (float*)(w + 72089600);                     // 512 KB
  float* kv2  = (float*)(w + 72613888);                     // 2 MB
  float* v1p  = (float*)(w + 74711040);                     // 256 KB
  float* v2p  = (float*)(w + 74973184);                     // 1 MB -> 76021760
  // vT buffers reuse t1/t2 regions (dead after kv projections)
  unsigned short* vT1 = (unsigned short*)(w + 69468160);    // 128 KB (in t1)
  unsigned short* vT2 = (unsigned short*)(w + 69992448);    // 512 KB (in t2)

  cvt_w<<<256, 256, 0, stream>>>(q_w, kv1_w, kv2_w, proj_w, wq, wkv1, wkv2, wproj);
  transpose_bf<<<2048, 256, 0, stream>>>(x, xT);
  convgemm_mfma<8, 256><<<dim3(8, 32), 256, 0, stream>>>(xT, sr1_w, part1);
  convgemm_mfma<4, 256><<<dim3(32, 8), 256, 0, stream>>>(xT, sr2_w, part2);
  ln_gelu<<<1024, 128, 0, stream>>>(part1, 32, 1024, sr1_b, n1_g, n1_b, t1);
  ln_gelu<<<4096, 128, 0, stream>>>(part2, 8, 4096, sr2_b, n2_g, n2_b, t2);
  gemm_mfma<false><<<512, 256, 0, stream>>>(x, wq, nullptr, qbuf);
  gemm_mfma<false><<<8, 256, 0, stream>>>(t1, wkv1, nullptr, kv1);
  gemm_mfma<false><<<32, 256, 0, stream>>>(t2, wkv2, nullptr, kv2);
  dwconv<8><<<256, 256, 0, stream>>>(kv1, lc1_w, lc1_b, v1p);
  dwconv<16><<<1024, 256, 0, stream>>>(kv2, lc2_w, lc2_b, v2p);
  // v -> v^T (bf16, global; t1/t2 regions now dead)
  transpose_v<64><<<32, 256, 0, stream>>>(v1p, vT1);
  transpose_v<256><<<128, 256, 0, stream>>>(v2p, vT2);
  // MFMA fused attention v2
  attn_mfma<64, 0><<<dim3(64, 2, 16), 256, 0, stream>>>(qbuf, kv1, vT1, xcat);
  attn_mfma<256, 64><<<dim3(64, 2, 16), 256, 0, stream>>>(qbuf, kv2, vT2, xcat);
  gemm_mfma<true><<<512, 256, 0, stream>>>(xcat, wproj, proj_b, (float*)d_out);
}

// Round 11
// 182.173 us; speedup vs baseline: 1.1002x; 1.1002x over previous
//
#include <hip/hip_runtime.h>
#include <math.h>

#define B_ 16
#define N_ 4096

typedef __attribute__((ext_vector_type(8))) short short8v;
typedef __attribute__((ext_vector_type(4))) short short4v;
typedef __attribute__((ext_vector_type(4))) float f32x4;

__device__ __forceinline__ unsigned short f2bf(float f) {
  unsigned int u = __float_as_uint(f);
  return (unsigned short)((u + 0x7FFFu + ((u >> 16) & 1u)) >> 16);
}

// pack two fp32 -> one dword of two bf16 (lo = first, hi = second)
__device__ __forceinline__ unsigned int pk2(float a, float b) {
  return (unsigned int)f2bf(a) | ((unsigned int)f2bf(b) << 16);
}

// convert 8 consecutive fp32 -> bf16x8 fragment
__device__ __forceinline__ short8v cvt8f(const float* p) {
  float4 a = *reinterpret_cast<const float4*>(p);
  float4 b = *reinterpret_cast<const float4*>(p + 4);
  short8v r;
  r[0] = (short)f2bf(a.x); r[1] = (short)f2bf(a.y);
  r[2] = (short)f2bf(a.z); r[3] = (short)f2bf(a.w);
  r[4] = (short)f2bf(b.x); r[5] = (short)f2bf(b.y);
  r[6] = (short)f2bf(b.z); r[7] = (short)f2bf(b.w);
  return r;
}

// ---------------- square weights -> bf16 (R3 exact) ------------------------
__global__ __launch_bounds__(256) void cvt_w(const float* __restrict__ a,
    const float* __restrict__ b, const float* __restrict__ c,
    const float* __restrict__ d, unsigned short* __restrict__ wa,
    unsigned short* __restrict__ wb, unsigned short* __restrict__ wc,
    unsigned short* __restrict__ wd) {
  int i = blockIdx.x * 256 + threadIdx.x;
  int j = i & 16383;
  if (i < 16384) wa[j] = f2bf(a[j]);
  else if (i < 32768) wb[j] = f2bf(b[j]);
  else if (i < 49152) wc[j] = f2bf(c[j]);
  else wd[j] = f2bf(d[j]);
}

// ---- x (b,4096,128) fp32 -> xT (b,128,4096) bf16 (R7 exact) ---------------
__global__ __launch_bounds__(256) void transpose_bf(const float* __restrict__ x,
    unsigned short* __restrict__ xT) {
  __shared__ float lds[32 * 132];
  const int t = threadIdx.x;
  const int b = blockIdx.x >> 7, pt = blockIdx.x & 127;
  const int ptile = pt * 32;
  for (int i = t; i < 1024; i += 256) {
    int p = i >> 5, c4 = (i & 31) << 2;
    *reinterpret_cast<float4*>(&lds[p * 132 + c4]) =
        *reinterpret_cast<const float4*>(
            x + ((size_t)(b * 4096 + ptile + p)) * 128 + c4);
  }
  __syncthreads();
  const int c = t >> 1, p0 = (t & 1) * 16;
  unsigned short* dst = xT + (size_t)b * 524288 + c * 4096 + ptile + p0;
  uint4 u0, u1;
  u0.x = pk2(lds[(p0 + 0) * 132 + c], lds[(p0 + 1) * 132 + c]);
  u0.y = pk2(lds[(p0 + 2) * 132 + c], lds[(p0 + 3) * 132 + c]);
  u0.z = pk2(lds[(p0 + 4) * 132 + c], lds[(p0 + 5) * 132 + c]);
  u0.w = pk2(lds[(p0 + 6) * 132 + c], lds[(p0 + 7) * 132 + c]);
  u1.x = pk2(lds[(p0 + 8) * 132 + c], lds[(p0 + 9) * 132 + c]);
  u1.y = pk2(lds[(p0 + 10) * 132 + c], lds[(p0 + 11) * 132 + c]);
  u1.z = pk2(lds[(p0 + 12) * 132 + c], lds[(p0 + 13) * 132 + c]);
  u1.w = pk2(lds[(p0 + 14) * 132 + c], lds[(p0 + 15) * 132 + c]);
  *reinterpret_cast<uint4*>(dst) = u0;
  *reinterpret_cast<uint4*>(dst + 8) = u1;
}

// ---------- patchify conv as MFMA GEMM, K-split partials (R7 exact) --------
template <int SRV, int KSP>
__global__ __launch_bounds__(256) void convgemm_mfma(
    const unsigned short* __restrict__ xT, const float* __restrict__ W,
    float* __restrict__ part) {
  constexpr int WP = 64 / SRV;
  constexpr int M = WP * WP;
  constexpr int ROWS = B_ * M;
  constexpr int SS = SRV * SRV;
  constexpr int KTOT = 128 * SS;
  constexpr int LSS = (SRV == 8) ? 6 : 4;
  constexpr int LM = (SRV == 8) ? 6 : 8;
  constexpr int LWP = (SRV == 8) ? 3 : 4;
  const int t = threadIdx.x;
  const int wid = t >> 6, lane = t & 63;
  const int lrow = lane & 15, lk = (lane >> 4) << 3;
  const int r0 = blockIdx.x * 128 + wid * 32;
  const int kb0 = blockIdx.y * KSP;
  int rbase[2], pixoff[2];
#pragma unroll
  for (int m = 0; m < 2; m++) {
    int row = r0 + m * 16 + lrow;
    int b = row >> LM, p = row & (M - 1);
    int ph = p >> LWP, pw = p & (WP - 1);
    rbase[m] = b << 19;
    pixoff[m] = (ph * SRV) * 64 + pw * SRV;
  }
  f32x4 acc[2][8];
#pragma unroll
  for (int m = 0; m < 2; m++)
#pragma unroll
    for (int n = 0; n < 8; n++) acc[m][n] = (f32x4)(0.f);
  for (int k0 = 0; k0 < KSP; k0 += 32) {
    int k = kb0 + k0 + lk;
    int ci = k >> LSS;
    int rem = k & (SS - 1);
    short8v a[2], bf[8];
#pragma unroll
    for (int m = 0; m < 2; m++) {
      if constexpr (SRV == 8) {
        a[m] = *reinterpret_cast<const short8v*>(
            xT + (size_t)rbase[m] + ci * 4096 + pixoff[m] + (rem >> 3) * 64);
      } else {
        int kh0 = rem >> 2;
        short4v lo = *reinterpret_cast<const short4v*>(
            xT + (size_t)rbase[m] + ci * 4096 + pixoff[m] + kh0 * 64);
        short4v hi = *reinterpret_cast<const short4v*>(
            xT + (size_t)rbase[m] + ci * 4096 + pixoff[m] + (kh0 + 1) * 64);
        short8v av;
        av[0] = lo[0]; av[1] = lo[1]; av[2] = lo[2]; av[3] = lo[3];
        av[4] = hi[0]; av[5] = hi[1]; av[6] = hi[2]; av[7] = hi[3];
        a[m] = av;
      }
    }
#pragma unroll
    for (int n = 0; n < 8; n++)
      bf[n] = cvt8f(W + (size_t)(n * 16 + lrow) * KTOT + k);
#pragma unroll
    for (int m = 0; m < 2; m++)
#pragma unroll
      for (int n = 0; n < 8; n++)
        acc[m][n] = __builtin_amdgcn_mfma_f32_16x16x32_bf16(a[m], bf[n],
                                                            acc[m][n], 0, 0, 0);
  }
  const int rr = (lane >> 4) << 2;
#pragma unroll
  for (int m = 0; m < 2; m++)
#pragma unroll
    for (int n = 0; n < 8; n++) {
      int c = n * 16 + lrow;
#pragma unroll
      for (int j = 0; j < 4; j++)
        part[((size_t)blockIdx.y * ROWS + r0 + m * 16 + rr + j) * 128 + c] =
            acc[m][n][j];
    }
}

// ------- MFMA GEMM: out[r][c] = sum_k A[r][k] * W[c][k] --------------------
// A fp32 (cvt8f) or bf16 (direct short8v); out fp32 or bf16 (scalar f2bf,
// R1-proven). W bf16 [128][128].
template <bool A_BF16, bool OUT_BF16, bool HAS_BIAS>
__global__ __launch_bounds__(256) void gemm_mfma(const void* __restrict__ Araw,
    const unsigned short* __restrict__ W, const float* __restrict__ bias,
    void* __restrict__ out) {
  const int t = threadIdx.x;
  const int wid = t >> 6, lane = t & 63;
  const int lrow = lane & 15, lk = (lane >> 4) << 3;
  const int r0 = blockIdx.x * 128 + wid * 32;
  f32x4 acc[2][8];
#pragma unroll
  for (int m = 0; m < 2; m++)
#pragma unroll
    for (int n = 0; n < 8; n++) acc[m][n] = (f32x4)(0.f);
#pragma unroll
  for (int k0 = 0; k0 < 128; k0 += 32) {
    short8v a[2], bf[8];
#pragma unroll
    for (int m = 0; m < 2; m++) {
      if constexpr (A_BF16)
        a[m] = *reinterpret_cast<const short8v*>(
            (const unsigned short*)Araw + (size_t)(r0 + m * 16 + lrow) * 128 +
            k0 + lk);
      else
        a[m] = cvt8f((const float*)Araw + (size_t)(r0 + m * 16 + lrow) * 128 +
                     k0 + lk);
    }
#pragma unroll
    for (int n = 0; n < 8; n++)
      bf[n] = *reinterpret_cast<const short8v*>(
          W + (size_t)(n * 16 + lrow) * 128 + k0 + lk);
#pragma unroll
    for (int m = 0; m < 2; m++)
#pragma unroll
      for (int n = 0; n < 8; n++)
        acc[m][n] = __builtin_amdgcn_mfma_f32_16x16x32_bf16(a[m], bf[n],
                                                            acc[m][n], 0, 0, 0);
  }
  const int rr = (lane >> 4) << 2;
#pragma unroll
  for (int m = 0; m < 2; m++)
#pragma unroll
    for (int n = 0; n < 8; n++) {
      int c = n * 16 + lrow;
      float bv = HAS_BIAS ? bias[c] : 0.f;
#pragma unroll
      for (int j = 0; j < 4; j++) {
        size_t idx = (size_t)(r0 + m * 16 + rr + j) * 128 + c;
        float v = acc[m][n][j] + bv;
        if constexpr (OUT_BF16)
          ((unsigned short*)out)[idx] = f2bf(v);
        else
          ((float*)out)[idx] = v;
      }
    }
}

// ---- reduce K-split partials + conv bias, LayerNorm(128) + exact GELU -----
__global__ __launch_bounds__(128) void ln_gelu(const float* __restrict__ part,
    int nsplit, int rows, const float* __restrict__ cb,
    const float* __restrict__ g, const float* __restrict__ be,
    float* __restrict__ out) {
  const int row = blockIdx.x;
  const int t = threadIdx.x;
  float v = cb[t];
  for (int s = 0; s < nsplit; s++)
    v += part[((size_t)s * rows + row) * 128 + t];
  float sv = v, sq = v * v;
#pragma unroll
  for (int off = 32; off > 0; off >>= 1) {
    sv += __shfl_down(sv, off, 64);
    sq += __shfl_down(sq, off, 64);
  }
  __shared__ float red0[2], red1[2];
  if ((t & 63) == 0) {
    red0[t >> 6] = sv;
    red1[t >> 6] = sq;
  }
  __syncthreads();
  float mean = (red0[0] + red0[1]) * (1.f / 128.f);
  float var = (red1[0] + red1[1]) * (1.f / 128.f) - mean * mean;
  float y = (v - mean) * rsqrtf(var + 1e-5f) * g[t] + be[t];
  out[(size_t)row * 128 + t] = y * 0.5f * (1.f + erff(y * 0.70710678118f));
}

// --------- depthwise 3x3 (pad 1) on v; v' = v + conv (R3 exact) ------------
template <int WP>
__global__ __launch_bounds__(256) void dwconv(const float* __restrict__ kv,
    const float* __restrict__ lw, const float* __restrict__ lb,
    float* __restrict__ vp) {
  constexpr int M = WP * WP;
  constexpr int LM = (WP == 8) ? 6 : 8;
  constexpr int LWPc = (WP == 8) ? 3 : 4;
  int idx = blockIdx.x * 256 + threadIdx.x;
  int ch = idx & 63;
  int rest = idx >> 6;
  int m = rest & (M - 1);
  int bb = rest >> LM;
  int y = m >> LWPc, x0 = m & (WP - 1);
  float s = lb[ch];
#pragma unroll
  for (int ky = 0; ky < 3; ky++) {
    int yy = y + ky - 1;
    if (yy < 0 || yy >= WP) continue;
#pragma unroll
    for (int kx = 0; kx < 3; kx++) {
      int xx = x0 + kx - 1;
      if (xx < 0 || xx >= WP) continue;
      s += kv[((size_t)(bb * M + yy * WP + xx)) * 128 + 64 + ch] *
           lw[ch * 9 + ky * 3 + kx];
    }
  }
  vp[idx] = kv[((size_t)(bb * M + m)) * 128 + 64 + ch] + s;
}

// ---- vp (b, m, 64) fp32 -> vT (b, 64ch, M) bf16 (R10 exact) ---------------
template <int M>
__global__ __launch_bounds__(256) void transpose_v(const float* __restrict__ vp,
    unsigned short* __restrict__ vT) {
  constexpr int TPB = M / 32;
  __shared__ float lds[32 * 68];
  const int t = threadIdx.x;
  const int blk = blockIdx.x;
  const int b = blk / TPB, mt = blk % TPB;
  const int m0 = mt * 32;
  for (int i = t; i < 512; i += 256) {
    int m = i >> 4, c4 = (i & 15) << 2;
    *reinterpret_cast<float4*>(&lds[m * 68 + c4]) =
        *reinterpret_cast<const float4*>(vp + ((size_t)(b * M + m0 + m)) * 64 + c4);
  }
  __syncthreads();
  const int c = t >> 2, ms = (t & 3) * 8;
  unsigned short* dst = vT + ((size_t)b * 64 + c) * M + m0 + ms;
  uint4 u;
  u.x = pk2(lds[(ms + 0) * 68 + c], lds[(ms + 1) * 68 + c]);
  u.y = pk2(lds[(ms + 2) * 68 + c], lds[(ms + 3) * 68 + c]);
  u.z = pk2(lds[(ms + 4) * 68 + c], lds[(ms + 5) * 68 + c]);
  u.w = pk2(lds[(ms + 6) * 68 + c], lds[(ms + 7) * 68 + c]);
  *reinterpret_cast<uint4*>(dst) = u;
}

// ---- kv (b,m,128) fp32 cols 0..63 (= k) -> kb (b,m,64) bf16 ---------------
__global__ __launch_bounds__(256) void cvt_k(const float* __restrict__ kv,
    unsigned short* __restrict__ kb) {
  int i = blockIdx.x * 256 + threadIdx.x;
  int c4 = (i & 15) << 2;
  size_t bm = (size_t)(i >> 4);
  float4 v = *reinterpret_cast<const float4*>(kv + bm * 128 + c4);
  uint2 u;
  u.x = pk2(v.x, v.y);
  u.y = pk2(v.z, v.w);
  *reinterpret_cast<uint2*>(kb + bm * 64 + c4) = u;
}

// ------------- MFMA fused attention v3 (all-bf16 streams) ------------------
// Per block: 64 q-rows x BOTH heads of the branch (h-loop). No barrier.
// S^T = mfma(K,Q): lane holds q-col lrow, m-rows 4g+j. Softmax: 2 shfl_xor.
// P -> per-wave LDS (PSTR=M+8: 16B-aligned rows, 2-way banks = free).
// PV: out^T = mfma(Vt,P), Vt rows from global bf16 vT. Out: bf16 uint2.
template <int M, int QOFF>
__global__ __launch_bounds__(256) void attn_mfma(
    const unsigned short* __restrict__ qb, const unsigned short* __restrict__ kb,
    const unsigned short* __restrict__ vT, unsigned short* __restrict__ xc) {
  constexpr int PSTR = M + 8;
  constexpr int MT = M / 16;     // S^T m-tiles
  constexpr int PVS = M / 32;    // PV k-steps
  __shared__ unsigned short Pl[4][16 * PSTR];
  const int t = threadIdx.x;
  const int wid = t >> 6, lane = t & 63;
  const int lrow = lane & 15, g = lane >> 4;
  const int lk = g * 8;
  const int b = blockIdx.y;
  const size_t bm = (size_t)b * M;
  const int q0 = blockIdx.x * 64 + wid * 16;
  const size_t qrow = ((size_t)b * 4096 + q0 + lrow) * 128;
  const float scale = 0.17677669529663687f;  // 1/sqrt(32)
#pragma unroll
  for (int h = 0; h < 2; h++) {
    const int qoff = QOFF + h * 32;
    short8v qf = *reinterpret_cast<const short8v*>(qb + qrow + qoff + lk);
    // ---- S^T tiles: K fragments direct from global bf16 ----
    f32x4 s[MT];
#pragma unroll
    for (int mt = 0; mt < MT; mt++) {
      short8v kf = *reinterpret_cast<const short8v*>(
          kb + (bm + mt * 16 + lrow) * 64 + h * 32 + lk);
      s[mt] =
          __builtin_amdgcn_mfma_f32_16x16x32_bf16(kf, qf, (f32x4)(0.f), 0, 0, 0);
    }
    // ---- softmax over m ----
    float l = 0.f;
#pragma unroll
    for (int mt = 0; mt < MT; mt++)
#pragma unroll
      for (int j = 0; j < 4; j++) {
        float p = __expf(s[mt][j] * scale);
        s[mt][j] = p;
        l += p;
      }
    l += __shfl_xor(l, 16, 64);
    l += __shfl_xor(l, 32, 64);
    // ---- write P (bf16) to per-wave LDS ----
#pragma unroll
    for (int mt = 0; mt < MT; mt++) {
      uint2 pw;
      pw.x = pk2(s[mt][0], s[mt][1]);
      pw.y = pk2(s[mt][2], s[mt][3]);
      *reinterpret_cast<uint2*>(&Pl[wid][lrow * PSTR + mt * 16 + 4 * g]) = pw;
    }
    // ---- PV ----
    f32x4 o[2];
    o[0] = (f32x4)(0.f);
    o[1] = (f32x4)(0.f);
#pragma unroll
    for (int ks = 0; ks < PVS; ks++) {
      short8v pf = *reinterpret_cast<const short8v*>(
          &Pl[wid][lrow * PSTR + ks * 32 + lk]);
#pragma unroll
      for (int dt = 0; dt < 2; dt++) {
        short8v vf = *reinterpret_cast<const short8v*>(
            vT + ((size_t)b * 64 + h * 32 + dt * 16 + lrow) * M + ks * 32 + lk);
        o[dt] = __builtin_amdgcn_mfma_f32_16x16x32_bf16(vf, pf, o[dt], 0, 0, 0);
      }
    }
    // ---- store bf16: lane holds q-col lrow, d-rows dt*16 + 4g + j ----
    float linv = 1.f / l;
    unsigned short* orow = xc + qrow + qoff;
#pragma unroll
    for (int dt = 0; dt < 2; dt++) {
      uint2 u;
      u.x = pk2(o[dt][0] * linv, o[dt][1] * linv);
      u.y = pk2(o[dt][2] * linv, o[dt][3] * linv);
      *reinterpret_cast<uint2*>(orow + dt * 16 + 4 * g) = u;
    }
  }
}

extern "C" void kernel_launch(void* const* d_in, const int* in_sizes, int n_in,
                              void* d_out, int out_size, void* d_ws,
                              size_t ws_size, hipStream_t stream) {
  (void)in_sizes; (void)n_in; (void)out_size; (void)ws_size;
  const float* x      = (const float*)d_in[0];
  const float* q_w    = (const float*)d_in[1];
  const float* sr1_w  = (const float*)d_in[2];
  const float* sr1_b  = (const float*)d_in[3];
  const float* n1_g   = (const float*)d_in[4];
  const float* n1_b   = (const float*)d_in[5];
  const float* sr2_w  = (const float*)d_in[6];
  const float* sr2_b  = (const float*)d_in[7];
  const float* n2_g   = (const float*)d_in[8];
  const float* n2_b   = (const float*)d_in[9];
  const float* kv1_w  = (const float*)d_in[10];
  const float* kv2_w  = (const float*)d_in[11];
  const float* lc1_w  = (const float*)d_in[12];
  const float* lc1_b  = (const float*)d_in[13];
  const float* lc2_w  = (const float*)d_in[14];
  const float* lc2_b  = (const float*)d_in[15];
  const float* proj_w = (const float*)d_in[16];
  const float* proj_b = (const float*)d_in[17];

  char* w = (char*)d_ws;
  unsigned short* wq    = (unsigned short*)(w);             // 32 KB
  unsigned short* wkv1  = (unsigned short*)(w + 32768);
  unsigned short* wkv2  = (unsigned short*)(w + 65536);
  unsigned short* wproj = (unsigned short*)(w + 98304);     // ends 131072
  // region A (33.55 MB): xT during conv phase; then qb (bf16) + kb1/kb2
  unsigned short* xT  = (unsigned short*)(w + 131072);      // 16.78 MB
  unsigned short* qb  = (unsigned short*)(w + 131072);      // 16.78 MB (after conv)
  unsigned short* kb1 = (unsigned short*)(w + 16908288);    // 128 KB
  unsigned short* kb2 = (unsigned short*)(w + 17039360);    // 512 KB
  // region B (33.55 MB): conv partials, then xcat (bf16)
  float* part1 = (float*)(w + 33685504);                    // 16.78 MB
  float* part2 = (float*)(w + 33685504 + 16777216);         // 16.78 MB
  unsigned short* xcb = (unsigned short*)(w + 33685504);    // 16.78 MB (after ln)
  float* t1   = (float*)(w + 69468160);                     // 512 KB
  float* t2   = (float*)(w + 69992448);                     // 2 MB
  float* kv1  = (float*)(w + 72089600);                     // 512 KB
  float* kv2  = (float*)(w + 72613888);                     // 2 MB
  float* v1p  = (float*)(w + 74711040);                     // 256 KB
  float* v2p  = (float*)(w + 74973184);                     // 1 MB -> 76021760
  unsigned short* vT1 = (unsigned short*)(w + 69468160);    // in t1 (dead)
  unsigned short* vT2 = (unsigned short*)(w + 69992448);    // in t2 (dead)

  cvt_w<<<256, 256, 0, stream>>>(q_w, kv1_w, kv2_w, proj_w, wq, wkv1, wkv2, wproj);
  transpose_bf<<<2048, 256, 0, stream>>>(x, xT);
  convgemm_mfma<8, 256><<<dim3(8, 32), 256, 0, stream>>>(xT, sr1_w, part1);
  convgemm_mfma<4, 256><<<dim3(32, 8), 256, 0, stream>>>(xT, sr2_w, part2);
  ln_gelu<<<1024, 128, 0, stream>>>(part1, 32, 1024, sr1_b, n1_g, n1_b, t1);
  ln_gelu<<<4096, 128, 0, stream>>>(part2, 8, 4096, sr2_b, n2_g, n2_b, t2);
  // q = x @ q_w^T -> bf16 (overwrites xT, now dead)
  gemm_mfma<false, true, false><<<512, 256, 0, stream>>>(x, wq, nullptr, qb);
  gemm_mfma<false, false, false><<<8, 256, 0, stream>>>(t1, wkv1, nullptr, kv1);
  gemm_mfma<false, false, false><<<32, 256, 0, stream>>>(t2, wkv2, nullptr, kv2);
  dwconv<8><<<256, 256, 0, stream>>>(kv1, lc1_w, lc1_b, v1p);
  dwconv<16><<<1024, 256, 0, stream>>>(kv2, lc2_w, lc2_b, v2p);
  transpose_v<64><<<32, 256, 0, stream>>>(v1p, vT1);
  transpose_v<256><<<128, 256, 0, stream>>>(v2p, vT2);
  cvt_k<<<64, 256, 0, stream>>>(kv1, kb1);
  cvt_k<<<256, 256, 0, stream>>>(kv2, kb2);
  // MFMA fused attention v3 (bf16 q/k/v in, bf16 out; partials dead)
  attn_mfma<64, 0><<<dim3(64, 16), 256, 0, stream>>>(qb, kb1, vT1, xcb);
  attn_mfma<256, 64><<<dim3(64, 16), 256, 0, stream>>>(qb, kb2, vT2, xcb);
  // output projection from bf16 xcat
  gemm_mfma<true, false, true><<<512, 256, 0, stream>>>(xcb, wproj, proj_b,
                                                        (float*)d_out);
}

// Round 13
// 163.135 us; speedup vs baseline: 1.2286x; 1.1167x over previous
//
#include <hip/hip_runtime.h>
#include <math.h>

#define B_ 16
#define N_ 4096

typedef __attribute__((ext_vector_type(8))) short short8v;
typedef __attribute__((ext_vector_type(4))) short short4v;
typedef __attribute__((ext_vector_type(4))) float f32x4;

__device__ __forceinline__ unsigned short f2bf(float f) {
  unsigned int u = __float_as_uint(f);
  return (unsigned short)((u + 0x7FFFu + ((u >> 16) & 1u)) >> 16);
}

__device__ __forceinline__ unsigned int pk2(float a, float b) {
  return (unsigned int)f2bf(a) | ((unsigned int)f2bf(b) << 16);
}

__device__ __forceinline__ short8v cvt8f(const float* p) {
  float4 a = *reinterpret_cast<const float4*>(p);
  float4 b = *reinterpret_cast<const float4*>(p + 4);
  short8v r;
  r[0] = (short)f2bf(a.x); r[1] = (short)f2bf(a.y);
  r[2] = (short)f2bf(a.z); r[3] = (short)f2bf(a.w);
  r[4] = (short)f2bf(b.x); r[5] = (short)f2bf(b.y);
  r[6] = (short)f2bf(b.z); r[7] = (short)f2bf(b.w);
  return r;
}

// ---- ALL weights -> bf16, elementwise, raw layouts preserved --------------
// sizes: 4x16384 (square) + 1048576 (sr1: 128*128*64) + 262144 (sr2: 128*128*16)
// total 1376256 threads = 5376 blocks of 256.
__global__ __launch_bounds__(256) void cvt_all(const float* __restrict__ a,
    const float* __restrict__ b, const float* __restrict__ c,
    const float* __restrict__ d, const float* __restrict__ s1,
    const float* __restrict__ s2, unsigned short* __restrict__ wa,
    unsigned short* __restrict__ wb, unsigned short* __restrict__ wc,
    unsigned short* __restrict__ wd, unsigned short* __restrict__ w1,
    unsigned short* __restrict__ w2) {
  int i = blockIdx.x * 256 + threadIdx.x;
  if (i < 16384) wa[i] = f2bf(a[i]);
  else if (i < 32768) { int o = i - 16384; wb[o] = f2bf(b[o]); }
  else if (i < 49152) { int o = i - 32768; wc[o] = f2bf(c[o]); }
  else if (i < 65536) { int o = i - 49152; wd[o] = f2bf(d[o]); }
  else if (i < 65536 + 1048576) { int o = i - 65536; w1[o] = f2bf(s1[o]); }
  else { int o = i - 65536 - 1048576; w2[o] = f2bf(s2[o]); }  // 262144 elems
}

// ---- x (b,4096,128) fp32 -> xT (b,128,4096) bf16 (R7 exact) ---------------
__global__ __launch_bounds__(256) void transpose_bf(const float* __restrict__ x,
    unsigned short* __restrict__ xT) {
  __shared__ float lds[32 * 132];
  const int t = threadIdx.x;
  const int b = blockIdx.x >> 7, pt = blockIdx.x & 127;
  const int ptile = pt * 32;
  for (int i = t; i < 1024; i += 256) {
    int p = i >> 5, c4 = (i & 31) << 2;
    *reinterpret_cast<float4*>(&lds[p * 132 + c4]) =
        *reinterpret_cast<const float4*>(
            x + ((size_t)(b * 4096 + ptile + p)) * 128 + c4);
  }
  __syncthreads();
  const int c = t >> 1, p0 = (t & 1) * 16;
  unsigned short* dst = xT + (size_t)b * 524288 + c * 4096 + ptile + p0;
  uint4 u0, u1;
  u0.x = pk2(lds[(p0 + 0) * 132 + c], lds[(p0 + 1) * 132 + c]);
  u0.y = pk2(lds[(p0 + 2) * 132 + c], lds[(p0 + 3) * 132 + c]);
  u0.z = pk2(lds[(p0 + 4) * 132 + c], lds[(p0 + 5) * 132 + c]);
  u0.w = pk2(lds[(p0 + 6) * 132 + c], lds[(p0 + 7) * 132 + c]);
  u1.x = pk2(lds[(p0 + 8) * 132 + c], lds[(p0 + 9) * 132 + c]);
  u1.y = pk2(lds[(p0 + 10) * 132 + c], lds[(p0 + 11) * 132 + c]);
  u1.z = pk2(lds[(p0 + 12) * 132 + c], lds[(p0 + 13) * 132 + c]);
  u1.w = pk2(lds[(p0 + 14) * 132 + c], lds[(p0 + 15) * 132 + c]);
  *reinterpret_cast<uint4*>(dst) = u0;
  *reinterpret_cast<uint4*>(dst + 8) = u1;
}

// ---------- patchify conv as MFMA GEMM, K-split partials -------------------
// R7-proven structure; W bf16 (raw layout), direct short8v fragments.
template <int SRV, int KSP>
__global__ __launch_bounds__(256) void convgemm_mfma(
    const unsigned short* __restrict__ xT, const unsigned short* __restrict__ W,
    float* __restrict__ part) {
  constexpr int WP = 64 / SRV;
  constexpr int M = WP * WP;
  constexpr int ROWS = B_ * M;
  constexpr int SS = SRV * SRV;
  constexpr int KTOT = 128 * SS;
  constexpr int LSS = (SRV == 8) ? 6 : 4;
  constexpr int LM = (SRV == 8) ? 6 : 8;
  constexpr int LWP = (SRV == 8) ? 3 : 4;
  const int t = threadIdx.x;
  const int wid = t >> 6, lane = t & 63;
  const int lrow = lane & 15, lk = (lane >> 4) << 3;
  const int r0 = blockIdx.x * 128 + wid * 32;
  const int kb0 = blockIdx.y * KSP;
  int rbase[2], pixoff[2];
#pragma unroll
  for (int m = 0; m < 2; m++) {
    int row = r0 + m * 16 + lrow;
    int b = row >> LM, p = row & (M - 1);
    int ph = p >> LWP, pw = p & (WP - 1);
    rbase[m] = b << 19;
    pixoff[m] = (ph * SRV) * 64 + pw * SRV;
  }
  f32x4 acc[2][8];
#pragma unroll
  for (int m = 0; m < 2; m++)
#pragma unroll
    for (int n = 0; n < 8; n++) acc[m][n] = (f32x4)(0.f);
  for (int k0 = 0; k0 < KSP; k0 += 32) {
    int k = kb0 + k0 + lk;
    int ci = k >> LSS;
    int rem = k & (SS - 1);
    short8v a[2], bf[8];
#pragma unroll
    for (int m = 0; m < 2; m++) {
      if constexpr (SRV == 8) {
        a[m] = *reinterpret_cast<const short8v*>(
            xT + (size_t)rbase[m] + ci * 4096 + pixoff[m] + (rem >> 3) * 64);
      } else {
        int kh0 = rem >> 2;
        short4v lo = *reinterpret_cast<const short4v*>(
            xT + (size_t)rbase[m] + ci * 4096 + pixoff[m] + kh0 * 64);
        short4v hi = *reinterpret_cast<const short4v*>(
            xT + (size_t)rbase[m] + ci * 4096 + pixoff[m] + (kh0 + 1) * 64);
        short8v av;
        av[0] = lo[0]; av[1] = lo[1]; av[2] = lo[2]; av[3] = lo[3];
        av[4] = hi[0]; av[5] = hi[1]; av[6] = hi[2]; av[7] = hi[3];
        a[m] = av;
      }
    }
#pragma unroll
    for (int n = 0; n < 8; n++)
      bf[n] = *reinterpret_cast<const short8v*>(
          W + (size_t)(n * 16 + lrow) * KTOT + k);
#pragma unroll
    for (int m = 0; m < 2; m++)
#pragma unroll
      for (int n = 0; n < 8; n++)
        acc[m][n] = __builtin_amdgcn_mfma_f32_16x16x32_bf16(a[m], bf[n],
                                                            acc[m][n], 0, 0, 0);
  }
  const int rr = (lane >> 4) << 2;
#pragma unroll
  for (int m = 0; m < 2; m++)
#pragma unroll
    for (int n = 0; n < 8; n++) {
      int c = n * 16 + lrow;
#pragma unroll
      for (int j = 0; j < 4; j++)
        part[((size_t)blockIdx.y * ROWS + r0 + m * 16 + rr + j) * 128 + c] =
            acc[m][n][j];
    }
}

// ------- MFMA GEMM: out[r][c] = sum_k A[r][k] * W[c][k] (R11 exact) --------
template <bool A_BF16, bool OUT_BF16, bool HAS_BIAS>
__global__ __launch_bounds__(256) void gemm_mfma(const void* __restrict__ Araw,
    const unsigned short* __restrict__ W, const float* __restrict__ bias,
    void* __restrict__ out) {
  const int t = threadIdx.x;
  const int wid = t >> 6, lane = t & 63;
  const int lrow = lane & 15, lk = (lane >> 4) << 3;
  const int r0 = blockIdx.x * 128 + wid * 32;
  f32x4 acc[2][8];
#pragma unroll
  for (int m = 0; m < 2; m++)
#pragma unroll
    for (int n = 0; n < 8; n++) acc[m][n] = (f32x4)(0.f);
#pragma unroll
  for (int k0 = 0; k0 < 128; k0 += 32) {
    short8v a[2], bf[8];
#pragma unroll
    for (int m = 0; m < 2; m++) {
      if constexpr (A_BF16)
        a[m] = *reinterpret_cast<const short8v*>(
            (const unsigned short*)Araw + (size_t)(r0 + m * 16 + lrow) * 128 +
            k0 + lk);
      else
        a[m] = cvt8f((const float*)Araw + (size_t)(r0 + m * 16 + lrow) * 128 +
                     k0 + lk);
    }
#pragma unroll
    for (int n = 0; n < 8; n++)
      bf[n] = *reinterpret_cast<const short8v*>(
          W + (size_t)(n * 16 + lrow) * 128 + k0 + lk);
#pragma unroll
    for (int m = 0; m < 2; m++)
#pragma unroll
      for (int n = 0; n < 8; n++)
        acc[m][n] = __builtin_amdgcn_mfma_f32_16x16x32_bf16(a[m], bf[n],
                                                            acc[m][n], 0, 0, 0);
  }
  const int rr = (lane >> 4) << 2;
#pragma unroll
  for (int m = 0; m < 2; m++)
#pragma unroll
    for (int n = 0; n < 8; n++) {
      int c = n * 16 + lrow;
      float bv = HAS_BIAS ? bias[c] : 0.f;
#pragma unroll
      for (int j = 0; j < 4; j++) {
        size_t idx = (size_t)(r0 + m * 16 + rr + j) * 128 + c;
        float v = acc[m][n][j] + bv;
        if constexpr (OUT_BF16)
          ((unsigned short*)out)[idx] = f2bf(v);
        else
          ((float*)out)[idx] = v;
      }
    }
}

// ------- kv GEMM with split epilogue: cols 0..63 -> kb bf16, 64..127 -> vr fp32
__global__ __launch_bounds__(256) void gemm_kv(
    const unsigned short* __restrict__ A, const unsigned short* __restrict__ W,
    unsigned short* __restrict__ kb, float* __restrict__ vr) {
  const int t = threadIdx.x;
  const int wid = t >> 6, lane = t & 63;
  const int lrow = lane & 15, lk = (lane >> 4) << 3;
  const int r0 = blockIdx.x * 128 + wid * 32;
  f32x4 acc[2][8];
#pragma unroll
  for (int m = 0; m < 2; m++)
#pragma unroll
    for (int n = 0; n < 8; n++) acc[m][n] = (f32x4)(0.f);
#pragma unroll
  for (int k0 = 0; k0 < 128; k0 += 32) {
    short8v a[2], bf[8];
#pragma unroll
    for (int m = 0; m < 2; m++)
      a[m] = *reinterpret_cast<const short8v*>(
          A + (size_t)(r0 + m * 16 + lrow) * 128 + k0 + lk);
#pragma unroll
    for (int n = 0; n < 8; n++)
      bf[n] = *reinterpret_cast<const short8v*>(
          W + (size_t)(n * 16 + lrow) * 128 + k0 + lk);
#pragma unroll
    for (int m = 0; m < 2; m++)
#pragma unroll
      for (int n = 0; n < 8; n++)
        acc[m][n] = __builtin_amdgcn_mfma_f32_16x16x32_bf16(a[m], bf[n],
                                                            acc[m][n], 0, 0, 0);
  }
  const int rr = (lane >> 4) << 2;
#pragma unroll
  for (int m = 0; m < 2; m++)
#pragma unroll
    for (int n = 0; n < 8; n++) {
      int c = n * 16 + lrow;
#pragma unroll
      for (int j = 0; j < 4; j++) {
        int r = r0 + m * 16 + rr + j;
        float v = acc[m][n][j];
        if (c < 64)
          kb[(size_t)r * 64 + c] = f2bf(v);
        else
          vr[(size_t)r * 64 + (c - 64)] = v;
      }
    }
}

// ---- reduce K-split partials + conv bias, LN(128) + exact GELU -> bf16 ----
__global__ __launch_bounds__(128) void ln_gelu(const float* __restrict__ part,
    int nsplit, int rows, const float* __restrict__ cb,
    const float* __restrict__ g, const float* __restrict__ be,
    unsigned short* __restrict__ out) {
  const int row = blockIdx.x;
  const int t = threadIdx.x;
  float v = cb[t];
  for (int s = 0; s < nsplit; s++)
    v += part[((size_t)s * rows + row) * 128 + t];
  float sv = v, sq = v * v;
#pragma unroll
  for (int off = 32; off > 0; off >>= 1) {
    sv += __shfl_down(sv, off, 64);
    sq += __shfl_down(sq, off, 64);
  }
  __shared__ float red0[2], red1[2];
  if ((t & 63) == 0) {
    red0[t >> 6] = sv;
    red1[t >> 6] = sq;
  }
  __syncthreads();
  float mean = (red0[0] + red0[1]) * (1.f / 128.f);
  float var = (red1[0] + red1[1]) * (1.f / 128.f) - mean * mean;
  float y = (v - mean) * rsqrtf(var + 1e-5f) * g[t] + be[t];
  out[(size_t)row * 128 + t] = f2bf(y * 0.5f * (1.f + erff(y * 0.70710678118f)));
}

// --------- depthwise 3x3 (pad 1) on v (b,m,64 fp32); v' = v + conv ---------
template <int WP>
__global__ __launch_bounds__(256) void dwconv(const float* __restrict__ vr,
    const float* __restrict__ lw, const float* __restrict__ lb,
    float* __restrict__ vp) {
  constexpr int M = WP * WP;
  constexpr int LM = (WP == 8) ? 6 : 8;
  constexpr int LWPc = (WP == 8) ? 3 : 4;
  int idx = blockIdx.x * 256 + threadIdx.x;
  int ch = idx & 63;
  int rest = idx >> 6;
  int m = rest & (M - 1);
  int bb = rest >> LM;
  int y = m >> LWPc, x0 = m & (WP - 1);
  float s = lb[ch];
#pragma unroll
  for (int ky = 0; ky < 3; ky++) {
    int yy = y + ky - 1;
    if (yy < 0 || yy >= WP) continue;
#pragma unroll
    for (int kx = 0; kx < 3; kx++) {
      int xx = x0 + kx - 1;
      if (xx < 0 || xx >= WP) continue;
      s += vr[((size_t)(bb * M + yy * WP + xx)) * 64 + ch] *
           lw[ch * 9 + ky * 3 + kx];
    }
  }
  vp[idx] = vr[((size_t)(bb * M + m)) * 64 + ch] + s;
}

// ---- vp (b, m, 64) fp32 -> vT (b, 64ch, M) bf16 (R10 exact) ---------------
template <int M>
__global__ __launch_bounds__(256) void transpose_v(const float* __restrict__ vp,
    unsigned short* __restrict__ vT) {
  constexpr int TPB = M / 32;
  __shared__ float lds[32 * 68];
  const int t = threadIdx.x;
  const int blk = blockIdx.x;
  const int b = blk / TPB, mt = blk % TPB;
  const int m0 = mt * 32;
  for (int i = t; i < 512; i += 256) {
    int m = i >> 4, c4 = (i & 15) << 2;
    *reinterpret_cast<float4*>(&lds[m * 68 + c4]) =
        *reinterpret_cast<const float4*>(vp + ((size_t)(b * M + m0 + m)) * 64 + c4);
  }
  __syncthreads();
  const int c = t >> 2, ms = (t & 3) * 8;
  unsigned short* dst = vT + ((size_t)b * 64 + c) * M + m0 + ms;
  uint4 u;
  u.x = pk2(lds[(ms + 0) * 68 + c], lds[(ms + 1) * 68 + c]);
  u.y = pk2(lds[(ms + 2) * 68 + c], lds[(ms + 3) * 68 + c]);
  u.z = pk2(lds[(ms + 4) * 68 + c], lds[(ms + 5) * 68 + c]);
  u.w = pk2(lds[(ms + 6) * 68 + c], lds[(ms + 7) * 68 + c]);
  *reinterpret_cast<uint4*>(dst) = u;
}

// ------------- MFMA fused attention v3 (R11 exact) -------------------------
template <int M, int QOFF>
__global__ __launch_bounds__(256) void attn_mfma(
    const unsigned short* __restrict__ qb, const unsigned short* __restrict__ kb,
    const unsigned short* __restrict__ vT, unsigned short* __restrict__ xc) {
  constexpr int PSTR = M + 8;
  constexpr int MT = M / 16;
  constexpr int PVS = M / 32;
  __shared__ unsigned short Pl[4][16 * PSTR];
  const int t = threadIdx.x;
  const int wid = t >> 6, lane = t & 63;
  const int lrow = lane & 15, g = lane >> 4;
  const int lk = g * 8;
  const int b = blockIdx.y;
  const size_t bm = (size_t)b * M;
  const int q0 = blockIdx.x * 64 + wid * 16;
  const size_t qrow = ((size_t)b * 4096 + q0 + lrow) * 128;
  const float scale = 0.17677669529663687f;  // 1/sqrt(32)
#pragma unroll
  for (int h = 0; h < 2; h++) {
    const int qoff = QOFF + h * 32;
    short8v qf = *reinterpret_cast<const short8v*>(qb + qrow + qoff + lk);
    f32x4 s[MT];
#pragma unroll
    for (int mt = 0; mt < MT; mt++) {
      short8v kf = *reinterpret_cast<const short8v*>(
          kb + (bm + mt * 16 + lrow) * 64 + h * 32 + lk);
      s[mt] =
          __builtin_amdgcn_mfma_f32_16x16x32_bf16(kf, qf, (f32x4)(0.f), 0, 0, 0);
    }
    float l = 0.f;
#pragma unroll
    for (int mt = 0; mt < MT; mt++)
#pragma unroll
      for (int j = 0; j < 4; j++) {
        float p = __expf(s[mt][j] * scale);
        s[mt][j] = p;
        l += p;
      }
    l += __shfl_xor(l, 16, 64);
    l += __shfl_xor(l, 32, 64);
#pragma unroll
    for (int mt = 0; mt < MT; mt++) {
      uint2 pw;
      pw.x = pk2(s[mt][0], s[mt][1]);
      pw.y = pk2(s[mt][2], s[mt][3]);
      *reinterpret_cast<uint2*>(&Pl[wid][lrow * PSTR + mt * 16 + 4 * g]) = pw;
    }
    f32x4 o[2];
    o[0] = (f32x4)(0.f);
    o[1] = (f32x4)(0.f);
#pragma unroll
    for (int ks = 0; ks < PVS; ks++) {
      short8v pf = *reinterpret_cast<const short8v*>(
          &Pl[wid][lrow * PSTR + ks * 32 + lk]);
#pragma unroll
      for (int dt = 0; dt < 2; dt++) {
        short8v vf = *reinterpret_cast<const short8v*>(
            vT + ((size_t)b * 64 + h * 32 + dt * 16 + lrow) * M + ks * 32 + lk);
        o[dt] = __builtin_amdgcn_mfma_f32_16x16x32_bf16(vf, pf, o[dt], 0, 0, 0);
      }
    }
    float linv = 1.f / l;
    unsigned short* orow = xc + qrow + qoff;
#pragma unroll
    for (int dt = 0; dt < 2; dt++) {
      uint2 u;
      u.x = pk2(o[dt][0] * linv, o[dt][1] * linv);
      u.y = pk2(o[dt][2] * linv, o[dt][3] * linv);
      *reinterpret_cast<uint2*>(orow + dt * 16 + 4 * g) = u;
    }
  }
}

extern "C" void kernel_launch(void* const* d_in, const int* in_sizes, int n_in,
                              void* d_out, int out_size, void* d_ws,
                              size_t ws_size, hipStream_t stream) {
  (void)in_sizes; (void)n_in; (void)out_size; (void)ws_size;
  const float* x      = (const float*)d_in[0];
  const float* q_w    = (const float*)d_in[1];
  const float* sr1_w  = (const float*)d_in[2];
  const float* sr1_b  = (const float*)d_in[3];
  const float* n1_g   = (const float*)d_in[4];
  const float* n1_b   = (const float*)d_in[5];
  const float* sr2_w  = (const float*)d_in[6];
  const float* sr2_b  = (const float*)d_in[7];
  const float* n2_g   = (const float*)d_in[8];
  const float* n2_b   = (const float*)d_in[9];
  const float* kv1_w  = (const float*)d_in[10];
  const float* kv2_w  = (const float*)d_in[11];
  const float* lc1_w  = (const float*)d_in[12];
  const float* lc1_b  = (const float*)d_in[13];
  const float* lc2_w  = (const float*)d_in[14];
  const float* lc2_b  = (const float*)d_in[15];
  const float* proj_w = (const float*)d_in[16];
  const float* proj_b = (const float*)d_in[17];

  char* w = (char*)d_ws;
  unsigned short* wq    = (unsigned short*)(w);             // 32 KB
  unsigned short* wkv1  = (unsigned short*)(w + 32768);
  unsigned short* wkv2  = (unsigned short*)(w + 65536);
  unsigned short* wproj = (unsigned short*)(w + 98304);     // ends 131072
  unsigned short* w1b   = (unsigned short*)(w + 131072);    // 2 MB   -> 2228224
  unsigned short* w2b   = (unsigned short*)(w + 2228224);   // 512 KB -> 2752512
  // region A: xT during conv phase; then qb (bf16) at same spot
  unsigned short* xT  = (unsigned short*)(w + 2752512);     // 16.78 MB -> 19529728
  unsigned short* qb  = (unsigned short*)(w + 2752512);     // (after conv)
  unsigned short* kb1 = (unsigned short*)(w + 19529728);    // 128 KB -> 19660800
  unsigned short* kb2 = (unsigned short*)(w + 19660800);    // 512 KB -> 20185088
  // region B (33.55 MB): conv partials, then xcat (bf16)
  float* part1 = (float*)(w + 33685504);                    // 16.78 MB
  float* part2 = (float*)(w + 33685504 + 16777216);         // 16.78 MB
  unsigned short* xcb = (unsigned short*)(w + 33685504);    // (after ln)
  unsigned short* t1b = (unsigned short*)(w + 69468160);    // 256 KB -> 69730304
  unsigned short* t2b = (unsigned short*)(w + 69730304);    // 1 MB  -> 70778880
  float* vr1 = (float*)(w + 70778880);                      // 256 KB -> 71041024
  float* vr2 = (float*)(w + 71041024);                      // 1 MB  -> 72089600
  float* v1p = (float*)(w + 72089600);                      // 256 KB -> 72351744
  float* v2p = (float*)(w + 72351744);                      // 1 MB  -> 73400320
  unsigned short* vT1 = (unsigned short*)(w + 73400320);    // 128 KB -> 73531392
  unsigned short* vT2 = (unsigned short*)(w + 73531392);    // 512 KB -> 74055680

  // 1376256 elements total -> 5376 blocks (was 4608: sr2 tail unconverted!)
  cvt_all<<<5376, 256, 0, stream>>>(q_w, kv1_w, kv2_w, proj_w, sr1_w, sr2_w,
                                    wq, wkv1, wkv2, wproj, w1b, w2b);
  transpose_bf<<<2048, 256, 0, stream>>>(x, xT);
  convgemm_mfma<8, 256><<<dim3(8, 32), 256, 0, stream>>>(xT, w1b, part1);
  convgemm_mfma<4, 256><<<dim3(32, 8), 256, 0, stream>>>(xT, w2b, part2);
  ln_gelu<<<1024, 128, 0, stream>>>(part1, 32, 1024, sr1_b, n1_g, n1_b, t1b);
  ln_gelu<<<4096, 128, 0, stream>>>(part2, 8, 4096, sr2_b, n2_g, n2_b, t2b);
  // q = x @ q_w^T -> bf16 (overwrites xT, now dead)
  gemm_mfma<false, true, false><<<512, 256, 0, stream>>>(x, wq, nullptr, qb);
  // kv projections with split epilogue (kb bf16, vr fp32)
  gemm_kv<<<8, 256, 0, stream>>>(t1b, wkv1, kb1, vr1);
  gemm_kv<<<32, 256, 0, stream>>>(t2b, wkv2, kb2, vr2);
  dwconv<8><<<256, 256, 0, stream>>>(vr1, lc1_w, lc1_b, v1p);
  dwconv<16><<<1024, 256, 0, stream>>>(vr2, lc2_w, lc2_b, v2p);
  transpose_v<64><<<32, 256, 0, stream>>>(v1p, vT1);
  transpose_v<256><<<128, 256, 0, stream>>>(v2p, vT2);
  // MFMA fused attention (bf16 q/k/v in, bf16 out; partials dead)
  attn_mfma<64, 0><<<dim3(64, 16), 256, 0, stream>>>(qb, kb1, vT1, xcb);
  attn_mfma<256, 64><<<dim3(64, 16), 256, 0, stream>>>(qb, kb2, vT2, xcb);
  // output projection from bf16 xcat
  gemm_mfma<true, false, true><<<512, 256, 0, stream>>>(xcb, wproj, proj_b,
                                                        (float*)d_out);
}

// Round 14
// 135.489 us; speedup vs baseline: 1.4793x; 1.2040x over previous
//
#include <hip/hip_runtime.h>
#include <math.h>

#define B_ 16
#define N_ 4096

typedef __attribute__((ext_vector_type(8))) short short8v;
typedef __attribute__((ext_vector_type(4))) short short4v;
typedef __attribute__((ext_vector_type(4))) float f32x4;

__device__ __forceinline__ unsigned short f2bf(float f) {
  unsigned int u = __float_as_uint(f);
  return (unsigned short)((u + 0x7FFFu + ((u >> 16) & 1u)) >> 16);
}

__device__ __forceinline__ unsigned int pk2(float a, float b) {
  return (unsigned int)f2bf(a) | ((unsigned int)f2bf(b) << 16);
}

__device__ __forceinline__ short8v cvt8f(const float* p) {
  float4 a = *reinterpret_cast<const float4*>(p);
  float4 b = *reinterpret_cast<const float4*>(p + 4);
  short8v r;
  r[0] = (short)f2bf(a.x); r[1] = (short)f2bf(a.y);
  r[2] = (short)f2bf(a.z); r[3] = (short)f2bf(a.w);
  r[4] = (short)f2bf(b.x); r[5] = (short)f2bf(b.y);
  r[6] = (short)f2bf(b.z); r[7] = (short)f2bf(b.w);
  return r;
}

// ===== fused prep: x-transpose (blocks 0..2047) + weight cvt (2048..7423) ===
__global__ __launch_bounds__(256) void prep(const float* __restrict__ x,
    unsigned short* __restrict__ xT, const float* __restrict__ a,
    const float* __restrict__ b, const float* __restrict__ c,
    const float* __restrict__ d, const float* __restrict__ s1,
    const float* __restrict__ s2, unsigned short* __restrict__ wa,
    unsigned short* __restrict__ wb, unsigned short* __restrict__ wc,
    unsigned short* __restrict__ wd, unsigned short* __restrict__ w1,
    unsigned short* __restrict__ w2) {
  __shared__ float lds[32 * 132];
  const int t = threadIdx.x;
  if (blockIdx.x < 2048) {
    const int bb = blockIdx.x >> 7, pt = blockIdx.x & 127;
    const int ptile = pt * 32;
    for (int i = t; i < 1024; i += 256) {
      int p = i >> 5, c4 = (i & 31) << 2;
      *reinterpret_cast<float4*>(&lds[p * 132 + c4]) =
          *reinterpret_cast<const float4*>(
              x + ((size_t)(bb * 4096 + ptile + p)) * 128 + c4);
    }
    __syncthreads();
    const int ch = t >> 1, p0 = (t & 1) * 16;
    unsigned short* dst = xT + (size_t)bb * 524288 + ch * 4096 + ptile + p0;
    uint4 u0, u1;
    u0.x = pk2(lds[(p0 + 0) * 132 + ch], lds[(p0 + 1) * 132 + ch]);
    u0.y = pk2(lds[(p0 + 2) * 132 + ch], lds[(p0 + 3) * 132 + ch]);
    u0.z = pk2(lds[(p0 + 4) * 132 + ch], lds[(p0 + 5) * 132 + ch]);
    u0.w = pk2(lds[(p0 + 6) * 132 + ch], lds[(p0 + 7) * 132 + ch]);
    u1.x = pk2(lds[(p0 + 8) * 132 + ch], lds[(p0 + 9) * 132 + ch]);
    u1.y = pk2(lds[(p0 + 10) * 132 + ch], lds[(p0 + 11) * 132 + ch]);
    u1.z = pk2(lds[(p0 + 12) * 132 + ch], lds[(p0 + 13) * 132 + ch]);
    u1.w = pk2(lds[(p0 + 14) * 132 + ch], lds[(p0 + 15) * 132 + ch]);
    *reinterpret_cast<uint4*>(dst) = u0;
    *reinterpret_cast<uint4*>(dst + 8) = u1;
  } else {
    int i = (blockIdx.x - 2048) * 256 + t;
    if (i < 16384) wa[i] = f2bf(a[i]);
    else if (i < 32768) { int o = i - 16384; wb[o] = f2bf(b[o]); }
    else if (i < 49152) { int o = i - 32768; wc[o] = f2bf(c[o]); }
    else if (i < 65536) { int o = i - 49152; wd[o] = f2bf(d[o]); }
    else if (i < 65536 + 1048576) { int o = i - 65536; w1[o] = f2bf(s1[o]); }
    else { int o = i - 65536 - 1048576; w2[o] = f2bf(s2[o]); }  // 262144
  }
}

// ===== conv body (R13 exact, decoded indices) ==============================
template <int SRV, int KSP>
__device__ void conv_body(int bx, int by, const unsigned short* __restrict__ xT,
    const unsigned short* __restrict__ W, float* __restrict__ part) {
  constexpr int WP = 64 / SRV;
  constexpr int M = WP * WP;
  constexpr int ROWS = B_ * M;
  constexpr int SS = SRV * SRV;
  constexpr int KTOT = 128 * SS;
  constexpr int LSS = (SRV == 8) ? 6 : 4;
  constexpr int LM = (SRV == 8) ? 6 : 8;
  constexpr int LWP = (SRV == 8) ? 3 : 4;
  const int t = threadIdx.x;
  const int wid = t >> 6, lane = t & 63;
  const int lrow = lane & 15, lk = (lane >> 4) << 3;
  const int r0 = bx * 128 + wid * 32;
  const int kb0 = by * KSP;
  int rbase[2], pixoff[2];
#pragma unroll
  for (int m = 0; m < 2; m++) {
    int row = r0 + m * 16 + lrow;
    int b = row >> LM, p = row & (M - 1);
    int ph = p >> LWP, pw = p & (WP - 1);
    rbase[m] = b << 19;
    pixoff[m] = (ph * SRV) * 64 + pw * SRV;
  }
  f32x4 acc[2][8];
#pragma unroll
  for (int m = 0; m < 2; m++)
#pragma unroll
    for (int n = 0; n < 8; n++) acc[m][n] = (f32x4)(0.f);
  for (int k0 = 0; k0 < KSP; k0 += 32) {
    int k = kb0 + k0 + lk;
    int ci = k >> LSS;
    int rem = k & (SS - 1);
    short8v a[2], bf[8];
#pragma unroll
    for (int m = 0; m < 2; m++) {
      if constexpr (SRV == 8) {
        a[m] = *reinterpret_cast<const short8v*>(
            xT + (size_t)rbase[m] + ci * 4096 + pixoff[m] + (rem >> 3) * 64);
      } else {
        int kh0 = rem >> 2;
        short4v lo = *reinterpret_cast<const short4v*>(
            xT + (size_t)rbase[m] + ci * 4096 + pixoff[m] + kh0 * 64);
        short4v hi = *reinterpret_cast<const short4v*>(
            xT + (size_t)rbase[m] + ci * 4096 + pixoff[m] + (kh0 + 1) * 64);
        short8v av;
        av[0] = lo[0]; av[1] = lo[1]; av[2] = lo[2]; av[3] = lo[3];
        av[4] = hi[0]; av[5] = hi[1]; av[6] = hi[2]; av[7] = hi[3];
        a[m] = av;
      }
    }
#pragma unroll
    for (int n = 0; n < 8; n++)
      bf[n] = *reinterpret_cast<const short8v*>(
          W + (size_t)(n * 16 + lrow) * KTOT + k);
#pragma unroll
    for (int m = 0; m < 2; m++)
#pragma unroll
      for (int n = 0; n < 8; n++)
        acc[m][n] = __builtin_amdgcn_mfma_f32_16x16x32_bf16(a[m], bf[n],
                                                            acc[m][n], 0, 0, 0);
  }
  const int rr = (lane >> 4) << 2;
#pragma unroll
  for (int m = 0; m < 2; m++)
#pragma unroll
    for (int n = 0; n < 8; n++) {
      int cc = n * 16 + lrow;
#pragma unroll
      for (int j = 0; j < 4; j++)
        part[((size_t)by * ROWS + r0 + m * 16 + rr + j) * 128 + cc] =
            acc[m][n][j];
    }
}

// ===== square GEMM body (R13 exact) ========================================
template <bool A_BF16, bool OUT_BF16, bool HAS_BIAS>
__device__ void gemm_body(int bx, const void* __restrict__ Araw,
    const unsigned short* __restrict__ W, const float* __restrict__ bias,
    void* __restrict__ out) {
  const int t = threadIdx.x;
  const int wid = t >> 6, lane = t & 63;
  const int lrow = lane & 15, lk = (lane >> 4) << 3;
  const int r0 = bx * 128 + wid * 32;
  f32x4 acc[2][8];
#pragma unroll
  for (int m = 0; m < 2; m++)
#pragma unroll
    for (int n = 0; n < 8; n++) acc[m][n] = (f32x4)(0.f);
#pragma unroll
  for (int k0 = 0; k0 < 128; k0 += 32) {
    short8v a[2], bf[8];
#pragma unroll
    for (int m = 0; m < 2; m++) {
      if constexpr (A_BF16)
        a[m] = *reinterpret_cast<const short8v*>(
            (const unsigned short*)Araw + (size_t)(r0 + m * 16 + lrow) * 128 +
            k0 + lk);
      else
        a[m] = cvt8f((const float*)Araw + (size_t)(r0 + m * 16 + lrow) * 128 +
                     k0 + lk);
    }
#pragma unroll
    for (int n = 0; n < 8; n++)
      bf[n] = *reinterpret_cast<const short8v*>(
          W + (size_t)(n * 16 + lrow) * 128 + k0 + lk);
#pragma unroll
    for (int m = 0; m < 2; m++)
#pragma unroll
      for (int n = 0; n < 8; n++)
        acc[m][n] = __builtin_amdgcn_mfma_f32_16x16x32_bf16(a[m], bf[n],
                                                            acc[m][n], 0, 0, 0);
  }
  const int rr = (lane >> 4) << 2;
#pragma unroll
  for (int m = 0; m < 2; m++)
#pragma unroll
    for (int n = 0; n < 8; n++) {
      int cc = n * 16 + lrow;
      float bv = HAS_BIAS ? bias[cc] : 0.f;
#pragma unroll
      for (int j = 0; j < 4; j++) {
        size_t idx = (size_t)(r0 + m * 16 + rr + j) * 128 + cc;
        float v = acc[m][n][j] + bv;
        if constexpr (OUT_BF16)
          ((unsigned short*)out)[idx] = f2bf(v);
        else
          ((float*)out)[idx] = v;
      }
    }
}

// ===== fused conv1 + conv2 + q-gemm ========================================
__global__ __launch_bounds__(256) void conv_q(
    const unsigned short* __restrict__ xT, const unsigned short* __restrict__ w1b,
    const unsigned short* __restrict__ w2b, float* __restrict__ part1,
    float* __restrict__ part2, const float* __restrict__ x,
    const unsigned short* __restrict__ wq, unsigned short* __restrict__ qb) {
  const int bid = blockIdx.x;
  if (bid < 256) {
    conv_body<8, 256>(bid & 7, bid >> 3, xT, w1b, part1);
  } else if (bid < 512) {
    int j = bid - 256;
    conv_body<4, 256>(j & 31, j >> 5, xT, w2b, part2);
  } else {
    gemm_body<false, true, false>(bid - 512, x, wq, nullptr, qb);
  }
}

// ===== fused LN+GELU over both branches ====================================
__global__ __launch_bounds__(128) void ln_all(const float* __restrict__ part1,
    const float* __restrict__ part2, const float* __restrict__ cb1,
    const float* __restrict__ g1, const float* __restrict__ be1,
    const float* __restrict__ cb2, const float* __restrict__ g2,
    const float* __restrict__ be2, unsigned short* __restrict__ out1,
    unsigned short* __restrict__ out2) {
  const int t = threadIdx.x;
  int row = blockIdx.x;
  const float* part; const float *cb, *g, *be; unsigned short* out;
  int nsplit, rows;
  if (row < 1024) {
    part = part1; cb = cb1; g = g1; be = be1; out = out1;
    nsplit = 32; rows = 1024;
  } else {
    row -= 1024;
    part = part2; cb = cb2; g = g2; be = be2; out = out2;
    nsplit = 8; rows = 4096;
  }
  float v = cb[t];
  for (int s = 0; s < nsplit; s++)
    v += part[((size_t)s * rows + row) * 128 + t];
  float sv = v, sq = v * v;
#pragma unroll
  for (int off = 32; off > 0; off >>= 1) {
    sv += __shfl_down(sv, off, 64);
    sq += __shfl_down(sq, off, 64);
  }
  __shared__ float red0[2], red1[2];
  if ((t & 63) == 0) {
    red0[t >> 6] = sv;
    red1[t >> 6] = sq;
  }
  __syncthreads();
  float mean = (red0[0] + red0[1]) * (1.f / 128.f);
  float var = (red1[0] + red1[1]) * (1.f / 128.f) - mean * mean;
  float y = (v - mean) * rsqrtf(var + 1e-5f) * g[t] + be[t];
  out[(size_t)row * 128 + t] = f2bf(y * 0.5f * (1.f + erff(y * 0.70710678118f)));
}

// ===== kv GEMM body (split epilogue, R13 exact) ============================
__device__ void kv_body(int bx, const unsigned short* __restrict__ A,
    const unsigned short* __restrict__ W, unsigned short* __restrict__ kb,
    float* __restrict__ vr) {
  const int t = threadIdx.x;
  const int wid = t >> 6, lane = t & 63;
  const int lrow = lane & 15, lk = (lane >> 4) << 3;
  const int r0 = bx * 128 + wid * 32;
  f32x4 acc[2][8];
#pragma unroll
  for (int m = 0; m < 2; m++)
#pragma unroll
    for (int n = 0; n < 8; n++) acc[m][n] = (f32x4)(0.f);
#pragma unroll
  for (int k0 = 0; k0 < 128; k0 += 32) {
    short8v a[2], bf[8];
#pragma unroll
    for (int m = 0; m < 2; m++)
      a[m] = *reinterpret_cast<const short8v*>(
          A + (size_t)(r0 + m * 16 + lrow) * 128 + k0 + lk);
#pragma unroll
    for (int n = 0; n < 8; n++)
      bf[n] = *reinterpret_cast<const short8v*>(
          W + (size_t)(n * 16 + lrow) * 128 + k0 + lk);
#pragma unroll
    for (int m = 0; m < 2; m++)
#pragma unroll
      for (int n = 0; n < 8; n++)
        acc[m][n] = __builtin_amdgcn_mfma_f32_16x16x32_bf16(a[m], bf[n],
                                                            acc[m][n], 0, 0, 0);
  }
  const int rr = (lane >> 4) << 2;
#pragma unroll
  for (int m = 0; m < 2; m++)
#pragma unroll
    for (int n = 0; n < 8; n++) {
      int cc = n * 16 + lrow;
#pragma unroll
      for (int j = 0; j < 4; j++) {
        int r = r0 + m * 16 + rr + j;
        float v = acc[m][n][j];
        if (cc < 64)
          kb[(size_t)r * 64 + cc] = f2bf(v);
        else
          vr[(size_t)r * 64 + (cc - 64)] = v;
      }
    }
}

__global__ __launch_bounds__(256) void kv_all(
    const unsigned short* __restrict__ t1b, const unsigned short* __restrict__ wkv1,
    unsigned short* __restrict__ kb1, float* __restrict__ vr1,
    const unsigned short* __restrict__ t2b, const unsigned short* __restrict__ wkv2,
    unsigned short* __restrict__ kb2, float* __restrict__ vr2) {
  if (blockIdx.x < 8)
    kv_body(blockIdx.x, t1b, wkv1, kb1, vr1);
  else
    kv_body(blockIdx.x - 8, t2b, wkv2, kb2, vr2);
}

// ===== dwconv body (R13 exact) =============================================
template <int WP>
__device__ void dw_body(int idx, const float* __restrict__ vr,
    const float* __restrict__ lw, const float* __restrict__ lb,
    float* __restrict__ vp) {
  constexpr int M = WP * WP;
  constexpr int LM = (WP == 8) ? 6 : 8;
  constexpr int LWPc = (WP == 8) ? 3 : 4;
  int ch = idx & 63;
  int rest = idx >> 6;
  int m = rest & (M - 1);
  int bb = rest >> LM;
  int y = m >> LWPc, x0 = m & (WP - 1);
  float s = lb[ch];
#pragma unroll
  for (int ky = 0; ky < 3; ky++) {
    int yy = y + ky - 1;
    if (yy < 0 || yy >= WP) continue;
#pragma unroll
    for (int kx = 0; kx < 3; kx++) {
      int xx = x0 + kx - 1;
      if (xx < 0 || xx >= WP) continue;
      s += vr[((size_t)(bb * M + yy * WP + xx)) * 64 + ch] *
           lw[ch * 9 + ky * 3 + kx];
    }
  }
  vp[idx] = vr[((size_t)(bb * M + m)) * 64 + ch] + s;
}

__global__ __launch_bounds__(256) void dw_all(const float* __restrict__ vr1,
    const float* __restrict__ lw1, const float* __restrict__ lb1,
    float* __restrict__ v1p, const float* __restrict__ vr2,
    const float* __restrict__ lw2, const float* __restrict__ lb2,
    float* __restrict__ v2p) {
  if (blockIdx.x < 256)
    dw_body<8>(blockIdx.x * 256 + threadIdx.x, vr1, lw1, lb1, v1p);
  else
    dw_body<16>((blockIdx.x - 256) * 256 + threadIdx.x, vr2, lw2, lb2, v2p);
}

// ===== v-transpose body (R13 exact) ========================================
template <int M>
__device__ void tv_body(int blk, const float* __restrict__ vp,
    unsigned short* __restrict__ vT, float* lds) {
  constexpr int TPB = M / 32;
  const int t = threadIdx.x;
  const int b = blk / TPB, mt = blk % TPB;
  const int m0 = mt * 32;
  for (int i = t; i < 512; i += 256) {
    int m = i >> 4, c4 = (i & 15) << 2;
    *reinterpret_cast<float4*>(&lds[m * 68 + c4]) =
        *reinterpret_cast<const float4*>(vp + ((size_t)(b * M + m0 + m)) * 64 + c4);
  }
  __syncthreads();
  const int c = t >> 2, ms = (t & 3) * 8;
  unsigned short* dst = vT + ((size_t)b * 64 + c) * M + m0 + ms;
  uint4 u;
  u.x = pk2(lds[(ms + 0) * 68 + c], lds[(ms + 1) * 68 + c]);
  u.y = pk2(lds[(ms + 2) * 68 + c], lds[(ms + 3) * 68 + c]);
  u.z = pk2(lds[(ms + 4) * 68 + c], lds[(ms + 5) * 68 + c]);
  u.w = pk2(lds[(ms + 6) * 68 + c], lds[(ms + 7) * 68 + c]);
  *reinterpret_cast<uint4*>(dst) = u;
}

__global__ __launch_bounds__(256) void tv_all(const float* __restrict__ v1p,
    unsigned short* __restrict__ vT1, const float* __restrict__ v2p,
    unsigned short* __restrict__ vT2) {
  __shared__ float lds[32 * 68];
  if (blockIdx.x < 32)
    tv_body<64>(blockIdx.x, v1p, vT1, lds);
  else
    tv_body<256>(blockIdx.x - 32, v2p, vT2, lds);
}

// ===== attention body (R13 exact, Pl passed in) ============================
template <int M, int QOFF>
__device__ void attn_body(int bx, int b, const unsigned short* __restrict__ qb,
    const unsigned short* __restrict__ kb, const unsigned short* __restrict__ vT,
    unsigned short* __restrict__ xc, unsigned short* Pl) {
  constexpr int PSTR = M + 8;
  constexpr int MT = M / 16;
  constexpr int PVS = M / 32;
  const int t = threadIdx.x;
  const int wid = t >> 6, lane = t & 63;
  const int lrow = lane & 15, g = lane >> 4;
  const int lk = g * 8;
  unsigned short* Plw = Pl + wid * 16 * PSTR;
  const size_t bm = (size_t)b * M;
  const int q0 = bx * 64 + wid * 16;
  const size_t qrow = ((size_t)b * 4096 + q0 + lrow) * 128;
  const float scale = 0.17677669529663687f;  // 1/sqrt(32)
#pragma unroll
  for (int h = 0; h < 2; h++) {
    const int qoff = QOFF + h * 32;
    short8v qf = *reinterpret_cast<const short8v*>(qb + qrow + qoff + lk);
    f32x4 s[MT];
#pragma unroll
    for (int mt = 0; mt < MT; mt++) {
      short8v kf = *reinterpret_cast<const short8v*>(
          kb + (bm + mt * 16 + lrow) * 64 + h * 32 + lk);
      s[mt] =
          __builtin_amdgcn_mfma_f32_16x16x32_bf16(kf, qf, (f32x4)(0.f), 0, 0, 0);
    }
    float l = 0.f;
#pragma unroll
    for (int mt = 0; mt < MT; mt++)
#pragma unroll
      for (int j = 0; j < 4; j++) {
        float p = __expf(s[mt][j] * scale);
        s[mt][j] = p;
        l += p;
      }
    l += __shfl_xor(l, 16, 64);
    l += __shfl_xor(l, 32, 64);
#pragma unroll
    for (int mt = 0; mt < MT; mt++) {
      uint2 pw;
      pw.x = pk2(s[mt][0], s[mt][1]);
      pw.y = pk2(s[mt][2], s[mt][3]);
      *reinterpret_cast<uint2*>(&Plw[lrow * PSTR + mt * 16 + 4 * g]) = pw;
    }
    f32x4 o[2];
    o[0] = (f32x4)(0.f);
    o[1] = (f32x4)(0.f);
#pragma unroll
    for (int ks = 0; ks < PVS; ks++) {
      short8v pf = *reinterpret_cast<const short8v*>(
          &Plw[lrow * PSTR + ks * 32 + lk]);
#pragma unroll
      for (int dt = 0; dt < 2; dt++) {
        short8v vf = *reinterpret_cast<const short8v*>(
            vT + ((size_t)b * 64 + h * 32 + dt * 16 + lrow) * M + ks * 32 + lk);
        o[dt] = __builtin_amdgcn_mfma_f32_16x16x32_bf16(vf, pf, o[dt], 0, 0, 0);
      }
    }
    float linv = 1.f / l;
    unsigned short* orow = xc + qrow + qoff;
#pragma unroll
    for (int dt = 0; dt < 2; dt++) {
      uint2 u;
      u.x = pk2(o[dt][0] * linv, o[dt][1] * linv);
      u.y = pk2(o[dt][2] * linv, o[dt][3] * linv);
      *reinterpret_cast<uint2*>(orow + dt * 16 + 4 * g) = u;
    }
  }
}

__global__ __launch_bounds__(256) void attn_all(
    const unsigned short* __restrict__ qb, const unsigned short* __restrict__ kb1,
    const unsigned short* __restrict__ vT1, const unsigned short* __restrict__ kb2,
    const unsigned short* __restrict__ vT2, unsigned short* __restrict__ xc) {
  __shared__ unsigned short Pl[4 * 16 * 264];  // max PSTR=264 (M=256)
  if (blockIdx.z == 0)
    attn_body<64, 0>(blockIdx.x, blockIdx.y, qb, kb1, vT1, xc, Pl);
  else
    attn_body<256, 64>(blockIdx.x, blockIdx.y, qb, kb2, vT2, xc, Pl);
}

// ===== output projection ===================================================
__global__ __launch_bounds__(256) void proj(const unsigned short* __restrict__ A,
    const unsigned short* __restrict__ W, const float* __restrict__ bias,
    float* __restrict__ out) {
  gemm_body<true, false, true>(blockIdx.x, A, W, bias, out);
}

extern "C" void kernel_launch(void* const* d_in, const int* in_sizes, int n_in,
                              void* d_out, int out_size, void* d_ws,
                              size_t ws_size, hipStream_t stream) {
  (void)in_sizes; (void)n_in; (void)out_size; (void)ws_size;
  const float* x      = (const float*)d_in[0];
  const float* q_w    = (const float*)d_in[1];
  const float* sr1_w  = (const float*)d_in[2];
  const float* sr1_b  = (const float*)d_in[3];
  const float* n1_g   = (const float*)d_in[4];
  const float* n1_b   = (const float*)d_in[5];
  const float* sr2_w  = (const float*)d_in[6];
  const float* sr2_b  = (const float*)d_in[7];
  const float* n2_g   = (const float*)d_in[8];
  const float* n2_b   = (const float*)d_in[9];
  const float* kv1_w  = (const float*)d_in[10];
  const float* kv2_w  = (const float*)d_in[11];
  const float* lc1_w  = (const float*)d_in[12];
  const float* lc1_b  = (const float*)d_in[13];
  const float* lc2_w  = (const float*)d_in[14];
  const float* lc2_b  = (const float*)d_in[15];
  const float* proj_w = (const float*)d_in[16];
  const float* proj_b = (const float*)d_in[17];

  char* w = (char*)d_ws;
  unsigned short* wq    = (unsigned short*)(w);             // 32 KB
  unsigned short* wkv1  = (unsigned short*)(w + 32768);
  unsigned short* wkv2  = (unsigned short*)(w + 65536);
  unsigned short* wproj = (unsigned short*)(w + 98304);     // ends 131072
  unsigned short* w1b   = (unsigned short*)(w + 131072);    // 2 MB   -> 2228224
  unsigned short* w2b   = (unsigned short*)(w + 2228224);   // 512 KB -> 2752512
  unsigned short* xT  = (unsigned short*)(w + 2752512);     // 16.78 MB -> 19529728
  unsigned short* qb  = (unsigned short*)(w + 2752512);     // (after conv)
  unsigned short* kb1 = (unsigned short*)(w + 19529728);    // 128 KB -> 19660800
  unsigned short* kb2 = (unsigned short*)(w + 19660800);    // 512 KB -> 20185088
  float* part1 = (float*)(w + 33685504);                    // 16.78 MB
  float* part2 = (float*)(w + 33685504 + 16777216);         // 16.78 MB
  unsigned short* xcb = (unsigned short*)(w + 33685504);    // (after ln)
  unsigned short* t1b = (unsigned short*)(w + 69468160);    // 256 KB -> 69730304
  unsigned short* t2b = (unsigned short*)(w + 69730304);    // 1 MB  -> 70778880
  float* vr1 = (float*)(w + 70778880);                      // 256 KB -> 71041024
  float* vr2 = (float*)(w + 71041024);                      // 1 MB  -> 72089600
  float* v1p = (float*)(w + 72089600);                      // 256 KB -> 72351744
  float* v2p = (float*)(w + 72351744);                      // 1 MB  -> 73400320
  unsigned short* vT1 = (unsigned short*)(w + 73400320);    // 128 KB -> 73531392
  unsigned short* vT2 = (unsigned short*)(w + 73531392);    // 512 KB -> 74055680

  // 1: x-transpose + all weight converts (2048 + 5376 blocks)
  prep<<<7424, 256, 0, stream>>>(x, xT, q_w, kv1_w, kv2_w, proj_w, sr1_w, sr2_w,
                                 wq, wkv1, wkv2, wproj, w1b, w2b);
  // 2: conv1 (256) + conv2 (256) + q-gemm (512) co-resident
  conv_q<<<1024, 256, 0, stream>>>(xT, w1b, w2b, part1, part2, x, wq, qb);
  // 3: LN+GELU both branches (1024 + 4096 rows)
  ln_all<<<5120, 128, 0, stream>>>(part1, part2, sr1_b, n1_g, n1_b, sr2_b, n2_g,
                                   n2_b, t1b, t2b);
  // 4: kv projections (8 + 32 blocks)
  kv_all<<<40, 256, 0, stream>>>(t1b, wkv1, kb1, vr1, t2b, wkv2, kb2, vr2);
  // 5: depthwise conv both branches (256 + 1024)
  dw_all<<<1280, 256, 0, stream>>>(vr1, lc1_w, lc1_b, v1p, vr2, lc2_w, lc2_b, v2p);
  // 6: v-transpose both branches (32 + 128)
  tv_all<<<160, 256, 0, stream>>>(v1p, vT1, v2p, vT2);
  // 7: attention both branches (64x16x2 blocks)
  attn_all<<<dim3(64, 16, 2), 256, 0, stream>>>(qb, kb1, vT1, kb2, vT2, xcb);
  // 8: output projection
  proj<<<512, 256, 0, stream>>>(xcb, wproj, proj_b, (float*)d_out);
}

// Round 15
// 133.743 us; speedup vs baseline: 1.4986x; 1.0130x over previous
//
#include <hip/hip_runtime.h>
#include <math.h>

#define B_ 16
#define N_ 4096

typedef __attribute__((ext_vector_type(8))) short short8v;
typedef __attribute__((ext_vector_type(4))) short short4v;
typedef __attribute__((ext_vector_type(4))) float f32x4;

__device__ __forceinline__ unsigned short f2bf(float f) {
  unsigned int u = __float_as_uint(f);
  return (unsigned short)((u + 0x7FFFu + ((u >> 16) & 1u)) >> 16);
}

__device__ __forceinline__ unsigned int pk2(float a, float b) {
  return (unsigned int)f2bf(a) | ((unsigned int)f2bf(b) << 16);
}

__device__ __forceinline__ short8v cvt8f(const float* p) {
  float4 a = *reinterpret_cast<const float4*>(p);
  float4 b = *reinterpret_cast<const float4*>(p + 4);
  short8v r;
  r[0] = (short)f2bf(a.x); r[1] = (short)f2bf(a.y);
  r[2] = (short)f2bf(a.z); r[3] = (short)f2bf(a.w);
  r[4] = (short)f2bf(b.x); r[5] = (short)f2bf(b.y);
  r[6] = (short)f2bf(b.z); r[7] = (short)f2bf(b.w);
  return r;
}

// ===== fused prep: x-transpose (blocks 0..2047) + weight cvt (2048..7423) ===
__global__ __launch_bounds__(256) void prep(const float* __restrict__ x,
    unsigned short* __restrict__ xT, const float* __restrict__ a,
    const float* __restrict__ b, const float* __restrict__ c,
    const float* __restrict__ d, const float* __restrict__ s1,
    const float* __restrict__ s2, unsigned short* __restrict__ wa,
    unsigned short* __restrict__ wb, unsigned short* __restrict__ wc,
    unsigned short* __restrict__ wd, unsigned short* __restrict__ w1,
    unsigned short* __restrict__ w2) {
  __shared__ float lds[32 * 132];
  const int t = threadIdx.x;
  if (blockIdx.x < 2048) {
    const int bb = blockIdx.x >> 7, pt = blockIdx.x & 127;
    const int ptile = pt * 32;
    for (int i = t; i < 1024; i += 256) {
      int p = i >> 5, c4 = (i & 31) << 2;
      *reinterpret_cast<float4*>(&lds[p * 132 + c4]) =
          *reinterpret_cast<const float4*>(
              x + ((size_t)(bb * 4096 + ptile + p)) * 128 + c4);
    }
    __syncthreads();
    const int ch = t >> 1, p0 = (t & 1) * 16;
    unsigned short* dst = xT + (size_t)bb * 524288 + ch * 4096 + ptile + p0;
    uint4 u0, u1;
    u0.x = pk2(lds[(p0 + 0) * 132 + ch], lds[(p0 + 1) * 132 + ch]);
    u0.y = pk2(lds[(p0 + 2) * 132 + ch], lds[(p0 + 3) * 132 + ch]);
    u0.z = pk2(lds[(p0 + 4) * 132 + ch], lds[(p0 + 5) * 132 + ch]);
    u0.w = pk2(lds[(p0 + 6) * 132 + ch], lds[(p0 + 7) * 132 + ch]);
    u1.x = pk2(lds[(p0 + 8) * 132 + ch], lds[(p0 + 9) * 132 + ch]);
    u1.y = pk2(lds[(p0 + 10) * 132 + ch], lds[(p0 + 11) * 132 + ch]);
    u1.z = pk2(lds[(p0 + 12) * 132 + ch], lds[(p0 + 13) * 132 + ch]);
    u1.w = pk2(lds[(p0 + 14) * 132 + ch], lds[(p0 + 15) * 132 + ch]);
    *reinterpret_cast<uint4*>(dst) = u0;
    *reinterpret_cast<uint4*>(dst + 8) = u1;
  } else {
    int i = (blockIdx.x - 2048) * 256 + t;
    if (i < 16384) wa[i] = f2bf(a[i]);
    else if (i < 32768) { int o = i - 16384; wb[o] = f2bf(b[o]); }
    else if (i < 49152) { int o = i - 32768; wc[o] = f2bf(c[o]); }
    else if (i < 65536) { int o = i - 49152; wd[o] = f2bf(d[o]); }
    else if (i < 65536 + 1048576) { int o = i - 65536; w1[o] = f2bf(s1[o]); }
    else { int o = i - 65536 - 1048576; w2[o] = f2bf(s2[o]); }  // 262144
  }
}

// ===== conv body (R13 exact, decoded indices) ==============================
template <int SRV, int KSP>
__device__ void conv_body(int bx, int by, const unsigned short* __restrict__ xT,
    const unsigned short* __restrict__ W, float* __restrict__ part) {
  constexpr int WP = 64 / SRV;
  constexpr int M = WP * WP;
  constexpr int ROWS = B_ * M;
  constexpr int SS = SRV * SRV;
  constexpr int KTOT = 128 * SS;
  constexpr int LSS = (SRV == 8) ? 6 : 4;
  constexpr int LM = (SRV == 8) ? 6 : 8;
  constexpr int LWP = (SRV == 8) ? 3 : 4;
  const int t = threadIdx.x;
  const int wid = t >> 6, lane = t & 63;
  const int lrow = lane & 15, lk = (lane >> 4) << 3;
  const int r0 = bx * 128 + wid * 32;
  const int kb0 = by * KSP;
  int rbase[2], pixoff[2];
#pragma unroll
  for (int m = 0; m < 2; m++) {
    int row = r0 + m * 16 + lrow;
    int b = row >> LM, p = row & (M - 1);
    int ph = p >> LWP, pw = p & (WP - 1);
    rbase[m] = b << 19;
    pixoff[m] = (ph * SRV) * 64 + pw * SRV;
  }
  f32x4 acc[2][8];
#pragma unroll
  for (int m = 0; m < 2; m++)
#pragma unroll
    for (int n = 0; n < 8; n++) acc[m][n] = (f32x4)(0.f);
  for (int k0 = 0; k0 < KSP; k0 += 32) {
    int k = kb0 + k0 + lk;
    int ci = k >> LSS;
    int rem = k & (SS - 1);
    short8v a[2], bf[8];
#pragma unroll
    for (int m = 0; m < 2; m++) {
      if constexpr (SRV == 8) {
        a[m] = *reinterpret_cast<const short8v*>(
            xT + (size_t)rbase[m] + ci * 4096 + pixoff[m] + (rem >> 3) * 64);
      } else {
        int kh0 = rem >> 2;
        short4v lo = *reinterpret_cast<const short4v*>(
            xT + (size_t)rbase[m] + ci * 4096 + pixoff[m] + kh0 * 64);
        short4v hi = *reinterpret_cast<const short4v*>(
            xT + (size_t)rbase[m] + ci * 4096 + pixoff[m] + (kh0 + 1) * 64);
        short8v av;
        av[0] = lo[0]; av[1] = lo[1]; av[2] = lo[2]; av[3] = lo[3];
        av[4] = hi[0]; av[5] = hi[1]; av[6] = hi[2]; av[7] = hi[3];
        a[m] = av;
      }
    }
#pragma unroll
    for (int n = 0; n < 8; n++)
      bf[n] = *reinterpret_cast<const short8v*>(
          W + (size_t)(n * 16 + lrow) * KTOT + k);
#pragma unroll
    for (int m = 0; m < 2; m++)
#pragma unroll
      for (int n = 0; n < 8; n++)
        acc[m][n] = __builtin_amdgcn_mfma_f32_16x16x32_bf16(a[m], bf[n],
                                                            acc[m][n], 0, 0, 0);
  }
  const int rr = (lane >> 4) << 2;
#pragma unroll
  for (int m = 0; m < 2; m++)
#pragma unroll
    for (int n = 0; n < 8; n++) {
      int cc = n * 16 + lrow;
#pragma unroll
      for (int j = 0; j < 4; j++)
        part[((size_t)by * ROWS + r0 + m * 16 + rr + j) * 128 + cc] =
            acc[m][n][j];
    }
}

// ===== square GEMM body (R13 exact) ========================================
template <bool A_BF16, bool OUT_BF16, bool HAS_BIAS>
__device__ void gemm_body(int bx, const void* __restrict__ Araw,
    const unsigned short* __restrict__ W, const float* __restrict__ bias,
    void* __restrict__ out) {
  const int t = threadIdx.x;
  const int wid = t >> 6, lane = t & 63;
  const int lrow = lane & 15, lk = (lane >> 4) << 3;
  const int r0 = bx * 128 + wid * 32;
  f32x4 acc[2][8];
#pragma unroll
  for (int m = 0; m < 2; m++)
#pragma unroll
    for (int n = 0; n < 8; n++) acc[m][n] = (f32x4)(0.f);
#pragma unroll
  for (int k0 = 0; k0 < 128; k0 += 32) {
    short8v a[2], bf[8];
#pragma unroll
    for (int m = 0; m < 2; m++) {
      if constexpr (A_BF16)
        a[m] = *reinterpret_cast<const short8v*>(
            (const unsigned short*)Araw + (size_t)(r0 + m * 16 + lrow) * 128 +
            k0 + lk);
      else
        a[m] = cvt8f((const float*)Araw + (size_t)(r0 + m * 16 + lrow) * 128 +
                     k0 + lk);
    }
#pragma unroll
    for (int n = 0; n < 8; n++)
      bf[n] = *reinterpret_cast<const short8v*>(
          W + (size_t)(n * 16 + lrow) * 128 + k0 + lk);
#pragma unroll
    for (int m = 0; m < 2; m++)
#pragma unroll
      for (int n = 0; n < 8; n++)
        acc[m][n] = __builtin_amdgcn_mfma_f32_16x16x32_bf16(a[m], bf[n],
                                                            acc[m][n], 0, 0, 0);
  }
  const int rr = (lane >> 4) << 2;
#pragma unroll
  for (int m = 0; m < 2; m++)
#pragma unroll
    for (int n = 0; n < 8; n++) {
      int cc = n * 16 + lrow;
      float bv = HAS_BIAS ? bias[cc] : 0.f;
#pragma unroll
      for (int j = 0; j < 4; j++) {
        size_t idx = (size_t)(r0 + m * 16 + rr + j) * 128 + cc;
        float v = acc[m][n][j] + bv;
        if constexpr (OUT_BF16)
          ((unsigned short*)out)[idx] = f2bf(v);
        else
          ((float*)out)[idx] = v;
      }
    }
}

// ===== fused conv1 + conv2 + q-gemm ========================================
__global__ __launch_bounds__(256) void conv_q(
    const unsigned short* __restrict__ xT, const unsigned short* __restrict__ w1b,
    const unsigned short* __restrict__ w2b, float* __restrict__ part1,
    float* __restrict__ part2, const float* __restrict__ x,
    const unsigned short* __restrict__ wq, unsigned short* __restrict__ qb) {
  const int bid = blockIdx.x;
  if (bid < 256) {
    conv_body<8, 256>(bid & 7, bid >> 3, xT, w1b, part1);
  } else if (bid < 512) {
    int j = bid - 256;
    conv_body<4, 256>(j & 31, j >> 5, xT, w2b, part2);
  } else {
    gemm_body<false, true, false>(bid - 512, x, wq, nullptr, qb);
  }
}

// ===== fused LN+GELU over both branches ====================================
__global__ __launch_bounds__(128) void ln_all(const float* __restrict__ part1,
    const float* __restrict__ part2, const float* __restrict__ cb1,
    const float* __restrict__ g1, const float* __restrict__ be1,
    const float* __restrict__ cb2, const float* __restrict__ g2,
    const float* __restrict__ be2, unsigned short* __restrict__ out1,
    unsigned short* __restrict__ out2) {
  const int t = threadIdx.x;
  int row = blockIdx.x;
  const float* part; const float *cb, *g, *be; unsigned short* out;
  int nsplit, rows;
  if (row < 1024) {
    part = part1; cb = cb1; g = g1; be = be1; out = out1;
    nsplit = 32; rows = 1024;
  } else {
    row -= 1024;
    part = part2; cb = cb2; g = g2; be = be2; out = out2;
    nsplit = 8; rows = 4096;
  }
  float v = cb[t];
  for (int s = 0; s < nsplit; s++)
    v += part[((size_t)s * rows + row) * 128 + t];
  float sv = v, sq = v * v;
#pragma unroll
  for (int off = 32; off > 0; off >>= 1) {
    sv += __shfl_down(sv, off, 64);
    sq += __shfl_down(sq, off, 64);
  }
  __shared__ float red0[2], red1[2];
  if ((t & 63) == 0) {
    red0[t >> 6] = sv;
    red1[t >> 6] = sq;
  }
  __syncthreads();
  float mean = (red0[0] + red0[1]) * (1.f / 128.f);
  float var = (red1[0] + red1[1]) * (1.f / 128.f) - mean * mean;
  float y = (v - mean) * rsqrtf(var + 1e-5f) * g[t] + be[t];
  out[(size_t)row * 128 + t] = f2bf(y * 0.5f * (1.f + erff(y * 0.70710678118f)));
}

// ===== kv GEMM body (split epilogue, R13 exact) ============================
__device__ void kv_body(int bx, const unsigned short* __restrict__ A,
    const unsigned short* __restrict__ W, unsigned short* __restrict__ kb,
    float* __restrict__ vr) {
  const int t = threadIdx.x;
  const int wid = t >> 6, lane = t & 63;
  const int lrow = lane & 15, lk = (lane >> 4) << 3;
  const int r0 = bx * 128 + wid * 32;
  f32x4 acc[2][8];
#pragma unroll
  for (int m = 0; m < 2; m++)
#pragma unroll
    for (int n = 0; n < 8; n++) acc[m][n] = (f32x4)(0.f);
#pragma unroll
  for (int k0 = 0; k0 < 128; k0 += 32) {
    short8v a[2], bf[8];
#pragma unroll
    for (int m = 0; m < 2; m++)
      a[m] = *reinterpret_cast<const short8v*>(
          A + (size_t)(r0 + m * 16 + lrow) * 128 + k0 + lk);
#pragma unroll
    for (int n = 0; n < 8; n++)
      bf[n] = *reinterpret_cast<const short8v*>(
          W + (size_t)(n * 16 + lrow) * 128 + k0 + lk);
#pragma unroll
    for (int m = 0; m < 2; m++)
#pragma unroll
      for (int n = 0; n < 8; n++)
        acc[m][n] = __builtin_amdgcn_mfma_f32_16x16x32_bf16(a[m], bf[n],
                                                            acc[m][n], 0, 0, 0);
  }
  const int rr = (lane >> 4) << 2;
#pragma unroll
  for (int m = 0; m < 2; m++)
#pragma unroll
    for (int n = 0; n < 8; n++) {
      int cc = n * 16 + lrow;
#pragma unroll
      for (int j = 0; j < 4; j++) {
        int r = r0 + m * 16 + rr + j;
        float v = acc[m][n][j];
        if (cc < 64)
          kb[(size_t)r * 64 + cc] = f2bf(v);
        else
          vr[(size_t)r * 64 + (cc - 64)] = v;
      }
    }
}

__global__ __launch_bounds__(256) void kv_all(
    const unsigned short* __restrict__ t1b, const unsigned short* __restrict__ wkv1,
    unsigned short* __restrict__ kb1, float* __restrict__ vr1,
    const unsigned short* __restrict__ t2b, const unsigned short* __restrict__ wkv2,
    unsigned short* __restrict__ kb2, float* __restrict__ vr2) {
  if (blockIdx.x < 8)
    kv_body(blockIdx.x, t1b, wkv1, kb1, vr1);
  else
    kv_body(blockIdx.x - 8, t2b, wkv2, kb2, vr2);
}

// ===== dwconv body (R13 exact) =============================================
template <int WP>
__device__ void dw_body(int idx, const float* __restrict__ vr,
    const float* __restrict__ lw, const float* __restrict__ lb,
    float* __restrict__ vp) {
  constexpr int M = WP * WP;
  constexpr int LM = (WP == 8) ? 6 : 8;
  constexpr int LWPc = (WP == 8) ? 3 : 4;
  int ch = idx & 63;
  int rest = idx >> 6;
  int m = rest & (M - 1);
  int bb = rest >> LM;
  int y = m >> LWPc, x0 = m & (WP - 1);
  float s = lb[ch];
#pragma unroll
  for (int ky = 0; ky < 3; ky++) {
    int yy = y + ky - 1;
    if (yy < 0 || yy >= WP) continue;
#pragma unroll
    for (int kx = 0; kx < 3; kx++) {
      int xx = x0 + kx - 1;
      if (xx < 0 || xx >= WP) continue;
      s += vr[((size_t)(bb * M + yy * WP + xx)) * 64 + ch] *
           lw[ch * 9 + ky * 3 + kx];
    }
  }
  vp[idx] = vr[((size_t)(bb * M + m)) * 64 + ch] + s;
}

__global__ __launch_bounds__(256) void dw_all(const float* __restrict__ vr1,
    const float* __restrict__ lw1, const float* __restrict__ lb1,
    float* __restrict__ v1p, const float* __restrict__ vr2,
    const float* __restrict__ lw2, const float* __restrict__ lb2,
    float* __restrict__ v2p) {
  if (blockIdx.x < 256)
    dw_body<8>(blockIdx.x * 256 + threadIdx.x, vr1, lw1, lb1, v1p);
  else
    dw_body<16>((blockIdx.x - 256) * 256 + threadIdx.x, vr2, lw2, lb2, v2p);
}

// ===== v-transpose body (R13 exact) ========================================
template <int M>
__device__ void tv_body(int blk, const float* __restrict__ vp,
    unsigned short* __restrict__ vT, float* lds) {
  constexpr int TPB = M / 32;
  const int t = threadIdx.x;
  const int b = blk / TPB, mt = blk % TPB;
  const int m0 = mt * 32;
  for (int i = t; i < 512; i += 256) {
    int m = i >> 4, c4 = (i & 15) << 2;
    *reinterpret_cast<float4*>(&lds[m * 68 + c4]) =
        *reinterpret_cast<const float4*>(vp + ((size_t)(b * M + m0 + m)) * 64 + c4);
  }
  __syncthreads();
  const int c = t >> 2, ms = (t & 3) * 8;
  unsigned short* dst = vT + ((size_t)b * 64 + c) * M + m0 + ms;
  uint4 u;
  u.x = pk2(lds[(ms + 0) * 68 + c], lds[(ms + 1) * 68 + c]);
  u.y = pk2(lds[(ms + 2) * 68 + c], lds[(ms + 3) * 68 + c]);
  u.z = pk2(lds[(ms + 4) * 68 + c], lds[(ms + 5) * 68 + c]);
  u.w = pk2(lds[(ms + 6) * 68 + c], lds[(ms + 7) * 68 + c]);
  *reinterpret_cast<uint4*>(dst) = u;
}

__global__ __launch_bounds__(256) void tv_all(const float* __restrict__ v1p,
    unsigned short* __restrict__ vT1, const float* __restrict__ v2p,
    unsigned short* __restrict__ vT2) {
  __shared__ float lds[32 * 68];
  if (blockIdx.x < 32)
    tv_body<64>(blockIdx.x, v1p, vT1, lds);
  else
    tv_body<256>(blockIdx.x - 32, v2p, vT2, lds);
}

// ===== attention body v4: PV in m-halves (chain 8->4, LDS 33.8->17.4 KB) ===
template <int M, int QOFF>
__device__ void attn_body(int bx, int b, const unsigned short* __restrict__ qb,
    const unsigned short* __restrict__ kb, const unsigned short* __restrict__ vT,
    unsigned short* __restrict__ xc, unsigned short* Pl) {
  constexpr int HM = (M > 128) ? 128 : M;  // m-chunk processed per P-pass
  constexpr int NCH = M / HM;              // 1 or 2 chunks
  constexpr int PSTR = HM + 8;             // dword-stride 4 mod 32: 2-way, free
  constexpr int MT = M / 16;
  constexpr int HKS = HM / 32;             // PV k-steps per chunk
  const int t = threadIdx.x;
  const int wid = t >> 6, lane = t & 63;
  const int lrow = lane & 15, g = lane >> 4;
  const int lk = g * 8;
  unsigned short* Plw = Pl + wid * 16 * PSTR;
  const size_t bm = (size_t)b * M;
  const int q0 = bx * 64 + wid * 16;
  const size_t qrow = ((size_t)b * 4096 + q0 + lrow) * 128;
  const float scale = 0.17677669529663687f;  // 1/sqrt(32)
#pragma unroll
  for (int h = 0; h < 2; h++) {
    const int qoff = QOFF + h * 32;
    short8v qf = *reinterpret_cast<const short8v*>(qb + qrow + qoff + lk);
    f32x4 s[MT];
#pragma unroll
    for (int mt = 0; mt < MT; mt++) {
      short8v kf = *reinterpret_cast<const short8v*>(
          kb + (bm + mt * 16 + lrow) * 64 + h * 32 + lk);
      s[mt] =
          __builtin_amdgcn_mfma_f32_16x16x32_bf16(kf, qf, (f32x4)(0.f), 0, 0, 0);
    }
    float l = 0.f;
#pragma unroll
    for (int mt = 0; mt < MT; mt++)
#pragma unroll
      for (int j = 0; j < 4; j++) {
        float p = __expf(s[mt][j] * scale);
        s[mt][j] = p;
        l += p;
      }
    l += __shfl_xor(l, 16, 64);
    l += __shfl_xor(l, 32, 64);
    f32x4 o[2];
    o[0] = (f32x4)(0.f);
    o[1] = (f32x4)(0.f);
#pragma unroll
    for (int half = 0; half < NCH; half++) {
      // write this chunk's P rows (wave-private; same-wave LDS ops in-order)
#pragma unroll
      for (int mt2 = 0; mt2 < HM / 16; mt2++) {
        int mt = half * (HM / 16) + mt2;
        uint2 pw;
        pw.x = pk2(s[mt][0], s[mt][1]);
        pw.y = pk2(s[mt][2], s[mt][3]);
        *reinterpret_cast<uint2*>(&Plw[lrow * PSTR + mt2 * 16 + 4 * g]) = pw;
      }
      // PV partial with chunk-local accumulators (chain = HKS)
      f32x4 oh[2];
      oh[0] = (f32x4)(0.f);
      oh[1] = (f32x4)(0.f);
#pragma unroll
      for (int ks = 0; ks < HKS; ks++) {
        short8v pf = *reinterpret_cast<const short8v*>(
            &Plw[lrow * PSTR + ks * 32 + lk]);
#pragma unroll
        for (int dt = 0; dt < 2; dt++) {
          short8v vf = *reinterpret_cast<const short8v*>(
              vT + ((size_t)b * 64 + h * 32 + dt * 16 + lrow) * M +
              half * HM + ks * 32 + lk);
          oh[dt] = __builtin_amdgcn_mfma_f32_16x16x32_bf16(vf, pf, oh[dt],
                                                           0, 0, 0);
        }
      }
#pragma unroll
      for (int dt = 0; dt < 2; dt++) o[dt] += oh[dt];
    }
    float linv = 1.f / l;
    unsigned short* orow = xc + qrow + qoff;
#pragma unroll
    for (int dt = 0; dt < 2; dt++) {
      uint2 u;
      u.x = pk2(o[dt][0] * linv, o[dt][1] * linv);
      u.y = pk2(o[dt][2] * linv, o[dt][3] * linv);
      *reinterpret_cast<uint2*>(orow + dt * 16 + 4 * g) = u;
    }
  }
}

// flat grid, long (M=256) blocks dispatched first for balance
__global__ __launch_bounds__(256) void attn_all(
    const unsigned short* __restrict__ qb, const unsigned short* __restrict__ kb1,
    const unsigned short* __restrict__ vT1, const unsigned short* __restrict__ kb2,
    const unsigned short* __restrict__ vT2, unsigned short* __restrict__ xc) {
  __shared__ unsigned short Pl[4 * 16 * 136];  // 17408 B (PSTR<=136)
  const int bid = blockIdx.x;
  if (bid < 1024)
    attn_body<256, 64>(bid & 63, bid >> 6, qb, kb2, vT2, xc, Pl);
  else {
    int j = bid - 1024;
    attn_body<64, 0>(j & 63, j >> 6, qb, kb1, vT1, xc, Pl);
  }
}

// ===== output projection ===================================================
__global__ __launch_bounds__(256) void proj(const unsigned short* __restrict__ A,
    const unsigned short* __restrict__ W, const float* __restrict__ bias,
    float* __restrict__ out) {
  gemm_body<true, false, true>(blockIdx.x, A, W, bias, out);
}

extern "C" void kernel_launch(void* const* d_in, const int* in_sizes, int n_in,
                              void* d_out, int out_size, void* d_ws,
                              size_t ws_size, hipStream_t stream) {
  (void)in_sizes; (void)n_in; (void)out_size; (void)ws_size;
  const float* x      = (const float*)d_in[0];
  const float* q_w    = (const float*)d_in[1];
  const float* sr1_w  = (const float*)d_in[2];
  const float* sr1_b  = (const float*)d_in[3];
  const float* n1_g   = (const float*)d_in[4];
  const float* n1_b   = (const float*)d_in[5];
  const float* sr2_w  = (const float*)d_in[6];
  const float* sr2_b  = (const float*)d_in[7];
  const float* n2_g   = (const float*)d_in[8];
  const float* n2_b   = (const float*)d_in[9];
  const float* kv1_w  = (const float*)d_in[10];
  const float* kv2_w  = (const float*)d_in[11];
  const float* lc1_w  = (const float*)d_in[12];
  const float* lc1_b  = (const float*)d_in[13];
  const float* lc2_w  = (const float*)d_in[14];
  const float* lc2_b  = (const float*)d_in[15];
  const float* proj_w = (const float*)d_in[16];
  const float* proj_b = (const float*)d_in[17];

  char* w = (char*)d_ws;
  unsigned short* wq    = (unsigned short*)(w);             // 32 KB
  unsigned short* wkv1  = (unsigned short*)(w + 32768);
  unsigned short* wkv2  = (unsigned short*)(w + 65536);
  unsigned short* wproj = (unsigned short*)(w + 98304);     // ends 131072
  unsigned short* w1b   = (unsigned short*)(w + 131072);    // 2 MB   -> 2228224
  unsigned short* w2b   = (unsigned short*)(w + 2228224);   // 512 KB -> 2752512
  unsigned short* xT  = (unsigned short*)(w + 2752512);     // 16.78 MB -> 19529728
  unsigned short* qb  = (unsigned short*)(w + 2752512);     // (after conv)
  unsigned short* kb1 = (unsigned short*)(w + 19529728);    // 128 KB -> 19660800
  unsigned short* kb2 = (unsigned short*)(w + 19660800);    // 512 KB -> 20185088
  float* part1 = (float*)(w + 33685504);                    // 16.78 MB
  float* part2 = (float*)(w + 33685504 + 16777216);         // 16.78 MB
  unsigned short* xcb = (unsigned short*)(w + 33685504);    // (after ln)
  unsigned short* t1b = (unsigned short*)(w + 69468160);    // 256 KB -> 69730304
  unsigned short* t2b = (unsigned short*)(w + 69730304);    // 1 MB  -> 70778880
  float* vr1 = (float*)(w + 70778880);                      // 256 KB -> 71041024
  float* vr2 = (float*)(w + 71041024);                      // 1 MB  -> 72089600
  float* v1p = (float*)(w + 72089600);                      // 256 KB -> 72351744
  float* v2p = (float*)(w + 72351744);                      // 1 MB  -> 73400320
  unsigned short* vT1 = (unsigned short*)(w + 73400320);    // 128 KB -> 73531392
  unsigned short* vT2 = (unsigned short*)(w + 73531392);    // 512 KB -> 74055680

  prep<<<7424, 256, 0, stream>>>(x, xT, q_w, kv1_w, kv2_w, proj_w, sr1_w, sr2_w,
                                 wq, wkv1, wkv2, wproj, w1b, w2b);
  conv_q<<<1024, 256, 0, stream>>>(xT, w1b, w2b, part1, part2, x, wq, qb);
  ln_all<<<5120, 128, 0, stream>>>(part1, part2, sr1_b, n1_g, n1_b, sr2_b, n2_g,
                                   n2_b, t1b, t2b);
  kv_all<<<40, 256, 0, stream>>>(t1b, wkv1, kb1, vr1, t2b, wkv2, kb2, vr2);
  dw_all<<<1280, 256, 0, stream>>>(vr1, lc1_w, lc1_b, v1p, vr2, lc2_w, lc2_b, v2p);
  tv_all<<<160, 256, 0, stream>>>(v1p, vT1, v2p, vT2);
  attn_all<<<2048, 256, 0, stream>>>(qb, kb1, vT1, kb2, vT2, xcb);
  proj<<<512, 256, 0, stream>>>(xcb, wproj, proj_b, (float*)d_out);
}

// Round 16
// 124.239 us; speedup vs baseline: 1.6133x; 1.0765x over previous
//
#include <hip/hip_runtime.h>
#include <math.h>

#define B_ 16
#define N_ 4096

typedef __attribute__((ext_vector_type(8))) short short8v;
typedef __attribute__((ext_vector_type(4))) short short4v;
typedef __attribute__((ext_vector_type(4))) float f32x4;

__device__ __forceinline__ unsigned short f2bf(float f) {
  unsigned int u = __float_as_uint(f);
  return (unsigned short)((u + 0x7FFFu + ((u >> 16) & 1u)) >> 16);
}

__device__ __forceinline__ unsigned int pk2(float a, float b) {
  return (unsigned int)f2bf(a) | ((unsigned int)f2bf(b) << 16);
}

__device__ __forceinline__ short8v cvt8f(const float* p) {
  float4 a = *reinterpret_cast<const float4*>(p);
  float4 b = *reinterpret_cast<const float4*>(p + 4);
  short8v r;
  r[0] = (short)f2bf(a.x); r[1] = (short)f2bf(a.y);
  r[2] = (short)f2bf(a.z); r[3] = (short)f2bf(a.w);
  r[4] = (short)f2bf(b.x); r[5] = (short)f2bf(b.y);
  r[6] = (short)f2bf(b.z); r[7] = (short)f2bf(b.w);
  return r;
}

// ===== fused prep: x-transpose (blocks 0..2047) + weight cvt (2048..7423) ===
__global__ __launch_bounds__(256) void prep(const float* __restrict__ x,
    unsigned short* __restrict__ xT, const float* __restrict__ a,
    const float* __restrict__ b, const float* __restrict__ c,
    const float* __restrict__ d, const float* __restrict__ s1,
    const float* __restrict__ s2, unsigned short* __restrict__ wa,
    unsigned short* __restrict__ wb, unsigned short* __restrict__ wc,
    unsigned short* __restrict__ wd, unsigned short* __restrict__ w1,
    unsigned short* __restrict__ w2) {
  __shared__ float lds[32 * 132];
  const int t = threadIdx.x;
  if (blockIdx.x < 2048) {
    const int bb = blockIdx.x >> 7, pt = blockIdx.x & 127;
    const int ptile = pt * 32;
    for (int i = t; i < 1024; i += 256) {
      int p = i >> 5, c4 = (i & 31) << 2;
      *reinterpret_cast<float4*>(&lds[p * 132 + c4]) =
          *reinterpret_cast<const float4*>(
              x + ((size_t)(bb * 4096 + ptile + p)) * 128 + c4);
    }
    __syncthreads();
    const int ch = t >> 1, p0 = (t & 1) * 16;
    unsigned short* dst = xT + (size_t)bb * 524288 + ch * 4096 + ptile + p0;
    uint4 u0, u1;
    u0.x = pk2(lds[(p0 + 0) * 132 + ch], lds[(p0 + 1) * 132 + ch]);
    u0.y = pk2(lds[(p0 + 2) * 132 + ch], lds[(p0 + 3) * 132 + ch]);
    u0.z = pk2(lds[(p0 + 4) * 132 + ch], lds[(p0 + 5) * 132 + ch]);
    u0.w = pk2(lds[(p0 + 6) * 132 + ch], lds[(p0 + 7) * 132 + ch]);
    u1.x = pk2(lds[(p0 + 8) * 132 + ch], lds[(p0 + 9) * 132 + ch]);
    u1.y = pk2(lds[(p0 + 10) * 132 + ch], lds[(p0 + 11) * 132 + ch]);
    u1.z = pk2(lds[(p0 + 12) * 132 + ch], lds[(p0 + 13) * 132 + ch]);
    u1.w = pk2(lds[(p0 + 14) * 132 + ch], lds[(p0 + 15) * 132 + ch]);
    *reinterpret_cast<uint4*>(dst) = u0;
    *reinterpret_cast<uint4*>(dst + 8) = u1;
  } else {
    int i = (blockIdx.x - 2048) * 256 + t;
    if (i < 16384) wa[i] = f2bf(a[i]);
    else if (i < 32768) { int o = i - 16384; wb[o] = f2bf(b[o]); }
    else if (i < 49152) { int o = i - 32768; wc[o] = f2bf(c[o]); }
    else if (i < 65536) { int o = i - 49152; wd[o] = f2bf(d[o]); }
    else if (i < 65536 + 1048576) { int o = i - 65536; w1[o] = f2bf(s1[o]); }
    else { int o = i - 65536 - 1048576; w2[o] = f2bf(s2[o]); }  // 262144
  }
}

// ===== conv body (R13 exact, decoded indices) ==============================
template <int SRV, int KSP>
__device__ void conv_body(int bx, int by, const unsigned short* __restrict__ xT,
    const unsigned short* __restrict__ W, float* __restrict__ part) {
  constexpr int WP = 64 / SRV;
  constexpr int M = WP * WP;
  constexpr int ROWS = B_ * M;
  constexpr int SS = SRV * SRV;
  constexpr int KTOT = 128 * SS;
  constexpr int LSS = (SRV == 8) ? 6 : 4;
  constexpr int LM = (SRV == 8) ? 6 : 8;
  constexpr int LWP = (SRV == 8) ? 3 : 4;
  const int t = threadIdx.x;
  const int wid = t >> 6, lane = t & 63;
  const int lrow = lane & 15, lk = (lane >> 4) << 3;
  const int r0 = bx * 128 + wid * 32;
  const int kb0 = by * KSP;
  int rbase[2], pixoff[2];
#pragma unroll
  for (int m = 0; m < 2; m++) {
    int row = r0 + m * 16 + lrow;
    int b = row >> LM, p = row & (M - 1);
    int ph = p >> LWP, pw = p & (WP - 1);
    rbase[m] = b << 19;
    pixoff[m] = (ph * SRV) * 64 + pw * SRV;
  }
  f32x4 acc[2][8];
#pragma unroll
  for (int m = 0; m < 2; m++)
#pragma unroll
    for (int n = 0; n < 8; n++) acc[m][n] = (f32x4)(0.f);
  for (int k0 = 0; k0 < KSP; k0 += 32) {
    int k = kb0 + k0 + lk;
    int ci = k >> LSS;
    int rem = k & (SS - 1);
    short8v a[2], bf[8];
#pragma unroll
    for (int m = 0; m < 2; m++) {
      if constexpr (SRV == 8) {
        a[m] = *reinterpret_cast<const short8v*>(
            xT + (size_t)rbase[m] + ci * 4096 + pixoff[m] + (rem >> 3) * 64);
      } else {
        int kh0 = rem >> 2;
        short4v lo = *reinterpret_cast<const short4v*>(
            xT + (size_t)rbase[m] + ci * 4096 + pixoff[m] + kh0 * 64);
        short4v hi = *reinterpret_cast<const short4v*>(
            xT + (size_t)rbase[m] + ci * 4096 + pixoff[m] + (kh0 + 1) * 64);
        short8v av;
        av[0] = lo[0]; av[1] = lo[1]; av[2] = lo[2]; av[3] = lo[3];
        av[4] = hi[0]; av[5] = hi[1]; av[6] = hi[2]; av[7] = hi[3];
        a[m] = av;
      }
    }
#pragma unroll
    for (int n = 0; n < 8; n++)
      bf[n] = *reinterpret_cast<const short8v*>(
          W + (size_t)(n * 16 + lrow) * KTOT + k);
#pragma unroll
    for (int m = 0; m < 2; m++)
#pragma unroll
      for (int n = 0; n < 8; n++)
        acc[m][n] = __builtin_amdgcn_mfma_f32_16x16x32_bf16(a[m], bf[n],
                                                            acc[m][n], 0, 0, 0);
  }
  const int rr = (lane >> 4) << 2;
#pragma unroll
  for (int m = 0; m < 2; m++)
#pragma unroll
    for (int n = 0; n < 8; n++) {
      int cc = n * 16 + lrow;
#pragma unroll
      for (int j = 0; j < 4; j++)
        part[((size_t)by * ROWS + r0 + m * 16 + rr + j) * 128 + cc] =
            acc[m][n][j];
    }
}

// ===== square GEMM body (R13 exact) ========================================
template <bool A_BF16, bool OUT_BF16, bool HAS_BIAS>
__device__ void gemm_body(int bx, const void* __restrict__ Araw,
    const unsigned short* __restrict__ W, const float* __restrict__ bias,
    void* __restrict__ out) {
  const int t = threadIdx.x;
  const int wid = t >> 6, lane = t & 63;
  const int lrow = lane & 15, lk = (lane >> 4) << 3;
  const int r0 = bx * 128 + wid * 32;
  f32x4 acc[2][8];
#pragma unroll
  for (int m = 0; m < 2; m++)
#pragma unroll
    for (int n = 0; n < 8; n++) acc[m][n] = (f32x4)(0.f);
#pragma unroll
  for (int k0 = 0; k0 < 128; k0 += 32) {
    short8v a[2], bf[8];
#pragma unroll
    for (int m = 0; m < 2; m++) {
      if constexpr (A_BF16)
        a[m] = *reinterpret_cast<const short8v*>(
            (const unsigned short*)Araw + (size_t)(r0 + m * 16 + lrow) * 128 +
            k0 + lk);
      else
        a[m] = cvt8f((const float*)Araw + (size_t)(r0 + m * 16 + lrow) * 128 +
                     k0 + lk);
    }
#pragma unroll
    for (int n = 0; n < 8; n++)
      bf[n] = *reinterpret_cast<const short8v*>(
          W + (size_t)(n * 16 + lrow) * 128 + k0 + lk);
#pragma unroll
    for (int m = 0; m < 2; m++)
#pragma unroll
      for (int n = 0; n < 8; n++)
        acc[m][n] = __builtin_amdgcn_mfma_f32_16x16x32_bf16(a[m], bf[n],
                                                            acc[m][n], 0, 0, 0);
  }
  const int rr = (lane >> 4) << 2;
#pragma unroll
  for (int m = 0; m < 2; m++)
#pragma unroll
    for (int n = 0; n < 8; n++) {
      int cc = n * 16 + lrow;
      float bv = HAS_BIAS ? bias[cc] : 0.f;
#pragma unroll
      for (int j = 0; j < 4; j++) {
        size_t idx = (size_t)(r0 + m * 16 + rr + j) * 128 + cc;
        float v = acc[m][n][j] + bv;
        if constexpr (OUT_BF16)
          ((unsigned short*)out)[idx] = f2bf(v);
        else
          ((float*)out)[idx] = v;
      }
    }
}

// ===== fused conv1 + conv2 + q-gemm ========================================
__global__ __launch_bounds__(256) void conv_q(
    const unsigned short* __restrict__ xT, const unsigned short* __restrict__ w1b,
    const unsigned short* __restrict__ w2b, float* __restrict__ part1,
    float* __restrict__ part2, const float* __restrict__ x,
    const unsigned short* __restrict__ wq, unsigned short* __restrict__ qb) {
  const int bid = blockIdx.x;
  if (bid < 256) {
    conv_body<8, 256>(bid & 7, bid >> 3, xT, w1b, part1);
  } else if (bid < 512) {
    int j = bid - 256;
    conv_body<4, 256>(j & 31, j >> 5, xT, w2b, part2);
  } else {
    gemm_body<false, true, false>(bid - 512, x, wq, nullptr, qb);
  }
}

// ===== fused LN+GELU over both branches ====================================
__global__ __launch_bounds__(128) void ln_all(const float* __restrict__ part1,
    const float* __restrict__ part2, const float* __restrict__ cb1,
    const float* __restrict__ g1, const float* __restrict__ be1,
    const float* __restrict__ cb2, const float* __restrict__ g2,
    const float* __restrict__ be2, unsigned short* __restrict__ out1,
    unsigned short* __restrict__ out2) {
  const int t = threadIdx.x;
  int row = blockIdx.x;
  const float* part; const float *cb, *g, *be; unsigned short* out;
  int nsplit, rows;
  if (row < 1024) {
    part = part1; cb = cb1; g = g1; be = be1; out = out1;
    nsplit = 32; rows = 1024;
  } else {
    row -= 1024;
    part = part2; cb = cb2; g = g2; be = be2; out = out2;
    nsplit = 8; rows = 4096;
  }
  float v = cb[t];
  for (int s = 0; s < nsplit; s++)
    v += part[((size_t)s * rows + row) * 128 + t];
  float sv = v, sq = v * v;
#pragma unroll
  for (int off = 32; off > 0; off >>= 1) {
    sv += __shfl_down(sv, off, 64);
    sq += __shfl_down(sq, off, 64);
  }
  __shared__ float red0[2], red1[2];
  if ((t & 63) == 0) {
    red0[t >> 6] = sv;
    red1[t >> 6] = sq;
  }
  __syncthreads();
  float mean = (red0[0] + red0[1]) * (1.f / 128.f);
  float var = (red1[0] + red1[1]) * (1.f / 128.f) - mean * mean;
  float y = (v - mean) * rsqrtf(var + 1e-5f) * g[t] + be[t];
  out[(size_t)row * 128 + t] = f2bf(y * 0.5f * (1.f + erff(y * 0.70710678118f)));
}

// ===== kv GEMM body (split epilogue, R13 exact) ============================
__device__ void kv_body(int bx, const unsigned short* __restrict__ A,
    const unsigned short* __restrict__ W, unsigned short* __restrict__ kb,
    float* __restrict__ vr) {
  const int t = threadIdx.x;
  const int wid = t >> 6, lane = t & 63;
  const int lrow = lane & 15, lk = (lane >> 4) << 3;
  const int r0 = bx * 128 + wid * 32;
  f32x4 acc[2][8];
#pragma unroll
  for (int m = 0; m < 2; m++)
#pragma unroll
    for (int n = 0; n < 8; n++) acc[m][n] = (f32x4)(0.f);
#pragma unroll
  for (int k0 = 0; k0 < 128; k0 += 32) {
    short8v a[2], bf[8];
#pragma unroll
    for (int m = 0; m < 2; m++)
      a[m] = *reinterpret_cast<const short8v*>(
          A + (size_t)(r0 + m * 16 + lrow) * 128 + k0 + lk);
#pragma unroll
    for (int n = 0; n < 8; n++)
      bf[n] = *reinterpret_cast<const short8v*>(
          W + (size_t)(n * 16 + lrow) * 128 + k0 + lk);
#pragma unroll
    for (int m = 0; m < 2; m++)
#pragma unroll
      for (int n = 0; n < 8; n++)
        acc[m][n] = __builtin_amdgcn_mfma_f32_16x16x32_bf16(a[m], bf[n],
                                                            acc[m][n], 0, 0, 0);
  }
  const int rr = (lane >> 4) << 2;
#pragma unroll
  for (int m = 0; m < 2; m++)
#pragma unroll
    for (int n = 0; n < 8; n++) {
      int cc = n * 16 + lrow;
#pragma unroll
      for (int j = 0; j < 4; j++) {
        int r = r0 + m * 16 + rr + j;
        float v = acc[m][n][j];
        if (cc < 64)
          kb[(size_t)r * 64 + cc] = f2bf(v);
        else
          vr[(size_t)r * 64 + (cc - 64)] = v;
      }
    }
}

__global__ __launch_bounds__(256) void kv_all(
    const unsigned short* __restrict__ t1b, const unsigned short* __restrict__ wkv1,
    unsigned short* __restrict__ kb1, float* __restrict__ vr1,
    const unsigned short* __restrict__ t2b, const unsigned short* __restrict__ wkv2,
    unsigned short* __restrict__ kb2, float* __restrict__ vr2) {
  if (blockIdx.x < 8)
    kv_body(blockIdx.x, t1b, wkv1, kb1, vr1);
  else
    kv_body(blockIdx.x - 8, t2b, wkv2, kb2, vr2);
}

// ===== dwconv body (R13 exact) =============================================
template <int WP>
__device__ void dw_body(int idx, const float* __restrict__ vr,
    const float* __restrict__ lw, const float* __restrict__ lb,
    float* __restrict__ vp) {
  constexpr int M = WP * WP;
  constexpr int LM = (WP == 8) ? 6 : 8;
  constexpr int LWPc = (WP == 8) ? 3 : 4;
  int ch = idx & 63;
  int rest = idx >> 6;
  int m = rest & (M - 1);
  int bb = rest >> LM;
  int y = m >> LWPc, x0 = m & (WP - 1);
  float s = lb[ch];
#pragma unroll
  for (int ky = 0; ky < 3; ky++) {
    int yy = y + ky - 1;
    if (yy < 0 || yy >= WP) continue;
#pragma unroll
    for (int kx = 0; kx < 3; kx++) {
      int xx = x0 + kx - 1;
      if (xx < 0 || xx >= WP) continue;
      s += vr[((size_t)(bb * M + yy * WP + xx)) * 64 + ch] *
           lw[ch * 9 + ky * 3 + kx];
    }
  }
  vp[idx] = vr[((size_t)(bb * M + m)) * 64 + ch] + s;
}

__global__ __launch_bounds__(256) void dw_all(const float* __restrict__ vr1,
    const float* __restrict__ lw1, const float* __restrict__ lb1,
    float* __restrict__ v1p, const float* __restrict__ vr2,
    const float* __restrict__ lw2, const float* __restrict__ lb2,
    float* __restrict__ v2p) {
  if (blockIdx.x < 256)
    dw_body<8>(blockIdx.x * 256 + threadIdx.x, vr1, lw1, lb1, v1p);
  else
    dw_body<16>((blockIdx.x - 256) * 256 + threadIdx.x, vr2, lw2, lb2, v2p);
}

// ===== v-transpose body (R13 exact) ========================================
template <int M>
__device__ void tv_body(int blk, const float* __restrict__ vp,
    unsigned short* __restrict__ vT, float* lds) {
  constexpr int TPB = M / 32;
  const int t = threadIdx.x;
  const int b = blk / TPB, mt = blk % TPB;
  const int m0 = mt * 32;
  for (int i = t; i < 512; i += 256) {
    int m = i >> 4, c4 = (i & 15) << 2;
    *reinterpret_cast<float4*>(&lds[m * 68 + c4]) =
        *reinterpret_cast<const float4*>(vp + ((size_t)(b * M + m0 + m)) * 64 + c4);
  }
  __syncthreads();
  const int c = t >> 2, ms = (t & 3) * 8;
  unsigned short* dst = vT + ((size_t)b * 64 + c) * M + m0 + ms;
  uint4 u;
  u.x = pk2(lds[(ms + 0) * 68 + c], lds[(ms + 1) * 68 + c]);
  u.y = pk2(lds[(ms + 2) * 68 + c], lds[(ms + 3) * 68 + c]);
  u.z = pk2(lds[(ms + 4) * 68 + c], lds[(ms + 5) * 68 + c]);
  u.w = pk2(lds[(ms + 6) * 68 + c], lds[(ms + 7) * 68 + c]);
  *reinterpret_cast<uint4*>(dst) = u;
}

__global__ __launch_bounds__(256) void tv_all(const float* __restrict__ v1p,
    unsigned short* __restrict__ vT1, const float* __restrict__ v2p,
    unsigned short* __restrict__ vT2) {
  __shared__ float lds[32 * 68];
  if (blockIdx.x < 32)
    tv_body<64>(blockIdx.x, v1p, vT1, lds);
  else
    tv_body<256>(blockIdx.x - 32, v2p, vT2, lds);
}

// ===== attention head v5: K from LDS (stride 72), PV in m-halves ===========
template <int M, int QOFF>
__device__ void attn_head(int b, int q0, int h,
    const unsigned short* __restrict__ qb, const unsigned short* Ks,
    const unsigned short* __restrict__ vT, unsigned short* __restrict__ xc,
    unsigned short* Plw) {
  constexpr int HM = (M > 128) ? 128 : M;
  constexpr int NCH = M / HM;
  constexpr int PSTR = HM + 8;
  constexpr int MT = M / 16;
  constexpr int HKS = HM / 32;
  const int lane = threadIdx.x & 63;
  const int lrow = lane & 15, g = lane >> 4;
  const int lk = g * 8;
  const size_t qrow = ((size_t)b * 4096 + q0 + lrow) * 128;
  const int qoff = QOFF + h * 32;
  const float scale = 0.17677669529663687f;  // 1/sqrt(32)
  short8v qf = *reinterpret_cast<const short8v*>(qb + qrow + qoff + lk);
  f32x4 s[MT];
#pragma unroll
  for (int mt = 0; mt < MT; mt++) {
    short8v kf = *reinterpret_cast<const short8v*>(
        Ks + (mt * 16 + lrow) * 72 + h * 32 + lk);
    s[mt] =
        __builtin_amdgcn_mfma_f32_16x16x32_bf16(kf, qf, (f32x4)(0.f), 0, 0, 0);
  }
  float l = 0.f;
#pragma unroll
  for (int mt = 0; mt < MT; mt++)
#pragma unroll
    for (int j = 0; j < 4; j++) {
      float p = __expf(s[mt][j] * scale);
      s[mt][j] = p;
      l += p;
    }
  l += __shfl_xor(l, 16, 64);
  l += __shfl_xor(l, 32, 64);
  f32x4 o[2];
  o[0] = (f32x4)(0.f);
  o[1] = (f32x4)(0.f);
#pragma unroll
  for (int half = 0; half < NCH; half++) {
#pragma unroll
    for (int mt2 = 0; mt2 < HM / 16; mt2++) {
      int mt = half * (HM / 16) + mt2;
      uint2 pw;
      pw.x = pk2(s[mt][0], s[mt][1]);
      pw.y = pk2(s[mt][2], s[mt][3]);
      *reinterpret_cast<uint2*>(&Plw[lrow * PSTR + mt2 * 16 + 4 * g]) = pw;
    }
    f32x4 oh[2];
    oh[0] = (f32x4)(0.f);
    oh[1] = (f32x4)(0.f);
#pragma unroll
    for (int ks = 0; ks < HKS; ks++) {
      short8v pf = *reinterpret_cast<const short8v*>(
          &Plw[lrow * PSTR + ks * 32 + lk]);
#pragma unroll
      for (int dt = 0; dt < 2; dt++) {
        short8v vf = *reinterpret_cast<const short8v*>(
            vT + ((size_t)b * 64 + h * 32 + dt * 16 + lrow) * M + half * HM +
            ks * 32 + lk);
        oh[dt] =
            __builtin_amdgcn_mfma_f32_16x16x32_bf16(vf, pf, oh[dt], 0, 0, 0);
      }
    }
#pragma unroll
    for (int dt = 0; dt < 2; dt++) o[dt] += oh[dt];
  }
  float linv = 1.f / l;
  unsigned short* orow = xc + qrow + qoff;
#pragma unroll
  for (int dt = 0; dt < 2; dt++) {
    uint2 u;
    u.x = pk2(o[dt][0] * linv, o[dt][1] * linv);
    u.y = pk2(o[dt][2] * linv, o[dt][3] * linv);
    *reinterpret_cast<uint2*>(orow + dt * 16 + 4 * g) = u;
  }
}

// one block per (b, 64 q-rows); all 4 heads; K staged in LDS cooperatively
__global__ __launch_bounds__(256) void attn_all(
    const unsigned short* __restrict__ qb, const unsigned short* __restrict__ kb1,
    const unsigned short* __restrict__ vT1, const unsigned short* __restrict__ kb2,
    const unsigned short* __restrict__ vT2, unsigned short* __restrict__ xc) {
  __shared__ unsigned short Ks2[256 * 72];      // 36 KB
  __shared__ unsigned short Ks1[64 * 72];       // 9 KB
  __shared__ unsigned short Pl[4 * 16 * 136];   // 17.4 KB
  const int t = threadIdx.x;
  const int b = blockIdx.x >> 6, qt = blockIdx.x & 63;
  // cooperative K staging (coalesced uint4)
  for (int i = t; i < 2048; i += 256) {
    int row = i >> 3, seg = i & 7;
    *reinterpret_cast<uint4*>(&Ks2[row * 72 + seg * 8]) =
        *reinterpret_cast<const uint4*>(kb2 + ((size_t)b * 256 + row) * 64 +
                                        seg * 8);
  }
  for (int i = t; i < 512; i += 256) {
    int row = i >> 3, seg = i & 7;
    *reinterpret_cast<uint4*>(&Ks1[row * 72 + seg * 8]) =
        *reinterpret_cast<const uint4*>(kb1 + ((size_t)b * 64 + row) * 64 +
                                        seg * 8);
  }
  __syncthreads();
  const int wid = t >> 6;
  unsigned short* Plw = Pl + wid * 16 * 136;
  const int q0 = qt * 64 + wid * 16;
  attn_head<256, 64>(b, q0, 0, qb, Ks2, vT2, xc, Plw);
  attn_head<256, 64>(b, q0, 1, qb, Ks2, vT2, xc, Plw);
  attn_head<64, 0>(b, q0, 0, qb, Ks1, vT1, xc, Plw);
  attn_head<64, 0>(b, q0, 1, qb, Ks1, vT1, xc, Plw);
}

// ===== output projection ===================================================
__global__ __launch_bounds__(256) void proj(const unsigned short* __restrict__ A,
    const unsigned short* __restrict__ W, const float* __restrict__ bias,
    float* __restrict__ out) {
  gemm_body<true, false, true>(blockIdx.x, A, W, bias, out);
}

extern "C" void kernel_launch(void* const* d_in, const int* in_sizes, int n_in,
                              void* d_out, int out_size, void* d_ws,
                              size_t ws_size, hipStream_t stream) {
  (void)in_sizes; (void)n_in; (void)out_size; (void)ws_size;
  const float* x      = (const float*)d_in[0];
  const float* q_w    = (const float*)d_in[1];
  const float* sr1_w  = (const float*)d_in[2];
  const float* sr1_b  = (const float*)d_in[3];
  const float* n1_g   = (const float*)d_in[4];
  const float* n1_b   = (const float*)d_in[5];
  const float* sr2_w  = (const float*)d_in[6];
  const float* sr2_b  = (const float*)d_in[7];
  const float* n2_g   = (const float*)d_in[8];
  const float* n2_b   = (const float*)d_in[9];
  const float* kv1_w  = (const float*)d_in[10];
  const float* kv2_w  = (const float*)d_in[11];
  const float* lc1_w  = (const float*)d_in[12];
  const float* lc1_b  = (const float*)d_in[13];
  const float* lc2_w  = (const float*)d_in[14];
  const float* lc2_b  = (const float*)d_in[15];
  const float* proj_w = (const float*)d_in[16];
  const float* proj_b = (const float*)d_in[17];

  char* w = (char*)d_ws;
  unsigned short* wq    = (unsigned short*)(w);             // 32 KB
  unsigned short* wkv1  = (unsigned short*)(w + 32768);
  unsigned short* wkv2  = (unsigned short*)(w + 65536);
  unsigned short* wproj = (unsigned short*)(w + 98304);     // ends 131072
  unsigned short* w1b   = (unsigned short*)(w + 131072);    // 2 MB   -> 2228224
  unsigned short* w2b   = (unsigned short*)(w + 2228224);   // 512 KB -> 2752512
  unsigned short* xT  = (unsigned short*)(w + 2752512);     // 16.78 MB -> 19529728
  unsigned short* qb  = (unsigned short*)(w + 2752512);     // (after conv)
  unsigned short* kb1 = (unsigned short*)(w + 19529728);    // 128 KB -> 19660800
  unsigned short* kb2 = (unsigned short*)(w + 19660800);    // 512 KB -> 20185088
  float* part1 = (float*)(w + 33685504);                    // 16.78 MB
  float* part2 = (float*)(w + 33685504 + 16777216);         // 16.78 MB
  unsigned short* xcb = (unsigned short*)(w + 33685504);    // (after ln)
  unsigned short* t1b = (unsigned short*)(w + 69468160);    // 256 KB -> 69730304
  unsigned short* t2b = (unsigned short*)(w + 69730304);    // 1 MB  -> 70778880
  float* vr1 = (float*)(w + 70778880);                      // 256 KB -> 71041024
  float* vr2 = (float*)(w + 71041024);                      // 1 MB  -> 72089600
  float* v1p = (float*)(w + 72089600);                      // 256 KB -> 72351744
  float* v2p = (float*)(w + 72351744);                      // 1 MB  -> 73400320
  unsigned short* vT1 = (unsigned short*)(w + 73400320);    // 128 KB -> 73531392
  unsigned short* vT2 = (unsigned short*)(w + 73531392);    // 512 KB -> 74055680

  prep<<<7424, 256, 0, stream>>>(x, xT, q_w, kv1_w, kv2_w, proj_w, sr1_w, sr2_w,
                                 wq, wkv1, wkv2, wproj, w1b, w2b);
  conv_q<<<1024, 256, 0, stream>>>(xT, w1b, w2b, part1, part2, x, wq, qb);
  ln_all<<<5120, 128, 0, stream>>>(part1, part2, sr1_b, n1_g, n1_b, sr2_b, n2_g,
                                   n2_b, t1b, t2b);
  kv_all<<<40, 256, 0, stream>>>(t1b, wkv1, kb1, vr1, t2b, wkv2, kb2, vr2);
  dw_all<<<1280, 256, 0, stream>>>(vr1, lc1_w, lc1_b, v1p, vr2, lc2_w, lc2_b, v2p);
  tv_all<<<160, 256, 0, stream>>>(v1p, vT1, v2p, vT2);
  attn_all<<<1024, 256, 0, stream>>>(qb, kb1, vT1, kb2, vT2, xcb);
  proj<<<512, 256, 0, stream>>>(xcb, wproj, proj_b, (float*)d_out);
}